// Round 1
// baseline (1915.712 us; speedup 1.0000x reference)
//
#include <hip/hip_runtime.h>
#include <math.h>

#define BATCH 8
#define NPTS  4096
#define NBR   16
#define MTOT  (BATCH * NPTS)   // 32768

// ---------------------------------------------------------------- KNN
// One block = 256 targets of one batch. All 4096 points (x,y,z,|p|^2) staged in
// LDS (64KB). Thread-per-target, register sorted top-16 (static indices only).
__global__ __launch_bounds__(256) void knn_kernel(const float* __restrict__ pos,
                                                  int* __restrict__ idxout) {
  __shared__ float4 pts[NPTS];
  int b = blockIdx.y;
  const float* pb = pos + (size_t)b * NPTS * 3;
  for (int i = threadIdx.x; i < NPTS; i += 256) {
    float x = pb[i * 3 + 0], y = pb[i * 3 + 1], z = pb[i * 3 + 2];
    pts[i] = make_float4(x, y, z, x * x + y * y + z * z);
  }
  __syncthreads();
  int p = blockIdx.x * 256 + threadIdx.x;
  float4 me = pts[p];
  float bd[NBR]; int bi[NBR];
#pragma unroll
  for (int j = 0; j < NBR; ++j) { bd[j] = 3.4e38f; bi[j] = 0; }
  for (int q = 0; q < NPTS; ++q) {
    float4 o = pts[q];
    float d2 = me.w + o.w - 2.f * (me.x * o.x + me.y * o.y + me.z * o.z);
    if (d2 < bd[NBR - 1] && q != p) {
      // sorted insert, fully unrolled (registers only). Stable w.r.t. ties:
      // equal d2 keeps earlier (smaller) index first, matching lax.top_k.
#pragma unroll
      for (int j = NBR - 1; j >= 1; --j) {
        float pj = bd[j - 1]; int pi = bi[j - 1];
        bool shift = (pj > d2);
        bool place = (!shift) && (bd[j] > d2);
        if (shift) { bd[j] = pj; bi[j] = pi; }
        else if (place) { bd[j] = d2; bi[j] = q; }
      }
      if (bd[0] > d2) { bd[0] = d2; bi[0] = q; }
    }
  }
  int* op = idxout + (size_t)(b * NPTS + p) * NBR;
#pragma unroll
  for (int j = 0; j < NBR; ++j) op[j] = bi[j];
}

// ---------------------------------------------------------------- GEMM (fp32)
// out[M,N] = X[M,K] @ W[K,N] + bias.  64x64 tile, BK=16, 256 thr, 4x4 micro.
__global__ __launch_bounds__(256) void gemm_bias(const float* __restrict__ X,
                                                 const float* __restrict__ W,
                                                 const float* __restrict__ bias,
                                                 float* __restrict__ out,
                                                 int K, int N) {
  __shared__ float As[16][68];  // stride 68: 16B-aligned float4 rows, 2-way banks
  __shared__ float Bs[16][64];
  int tid = threadIdx.x;
  int bm = blockIdx.x * 64;
  int bn = blockIdx.y * 64;
  int tr = tid >> 4, tc = tid & 15;
  float acc[4][4] = {{0.f}};
  for (int k0 = 0; k0 < K; k0 += 16) {
#pragma unroll
    for (int i = 0; i < 4; ++i) {
      int rr = (tid >> 4) + (i << 4);
      int kk = tid & 15;
      As[kk][rr] = (k0 + kk < K) ? X[(size_t)(bm + rr) * K + (k0 + kk)] : 0.f;
    }
#pragma unroll
    for (int i = 0; i < 4; ++i) {
      int kk = (tid >> 6) + (i << 2);
      int c  = tid & 63;
      Bs[kk][c] = (k0 + kk < K) ? W[(size_t)(k0 + kk) * N + (bn + c)] : 0.f;
    }
    __syncthreads();
#pragma unroll
    for (int kk = 0; kk < 16; ++kk) {
      float4 av = *(const float4*)&As[kk][tr << 2];
      float4 bv = *(const float4*)&Bs[kk][tc << 2];
      float a_[4] = {av.x, av.y, av.z, av.w};
      float b_[4] = {bv.x, bv.y, bv.z, bv.w};
#pragma unroll
      for (int i = 0; i < 4; ++i)
#pragma unroll
        for (int j = 0; j < 4; ++j)
          acc[i][j] += a_[i] * b_[j];
    }
    __syncthreads();
  }
  float4 bsv = *(const float4*)&bias[bn + (tc << 2)];
  float bb[4] = {bsv.x, bsv.y, bsv.z, bsv.w};
#pragma unroll
  for (int i = 0; i < 4; ++i) {
    float4 o;
    o.x = acc[i][0] + bb[0];
    o.y = acc[i][1] + bb[1];
    o.z = acc[i][2] + bb[2];
    o.w = acc[i][3] + bb[3];
    *(float4*)&out[(size_t)(bm + (tr << 2) + i) * N + bn + (tc << 2)] = o;
  }
}

// ---------------------------------------------------------------- Attention
// One wave per target: 16 neighbors x 4-lane dot groups for logits, shuffle
// softmax, then lane-per-channel PV gather. Adds skip (already in xout) + ReLU.
template <int DOUT>
__global__ __launch_bounds__(256) void attn_kernel(const float* __restrict__ qp,
                                                   const float* __restrict__ kp,
                                                   const float* __restrict__ vp,
                                                   const int* __restrict__ idx,
                                                   float* __restrict__ xout) {
  __shared__ float qrow[4][DOUT];
  __shared__ float aw[4][16];
  __shared__ int   sw[4][16];
  int lane = threadIdx.x & 63, wv = threadIdx.x >> 6;
  int t = blockIdx.x * 4 + wv;        // global target row in [0, MTOT)
  int b = t >> 12;                    // /4096
  if (lane < 16) sw[wv][lane] = (b << 12) + idx[t * 16 + lane];
  constexpr int F = DOUT / 4;
  if (lane < F)
    ((float4*)qrow[wv])[lane] = ((const float4*)(qp + (size_t)t * DOUT))[lane];
  __syncthreads();
  int j = lane >> 2, sub = lane & 3;
  int src = sw[wv][j];
  const float4* krow = (const float4*)(kp + (size_t)src * DOUT);
  const float4* q4 = (const float4*)qrow[wv];
  float acc = 0.f;
#pragma unroll
  for (int f = sub; f < F; f += 4) {
    float4 kk = krow[f], qq = q4[f];
    acc += qq.x * kk.x + qq.y * kk.y + qq.z * kk.z + qq.w * kk.w;
  }
  acc += __shfl_xor(acc, 1);
  acc += __shfl_xor(acc, 2);
  const float scale = (DOUT == 64) ? 0.125f
                    : (DOUT == 128) ? 0.08838834764831843f : 0.0625f;
  float logit = acc * scale;
  float mx = logit;
#pragma unroll
  for (int d = 4; d <= 32; d <<= 1) mx = fmaxf(mx, __shfl_xor(mx, d));
  float e = expf(logit - mx);
  float sm = e;
#pragma unroll
  for (int d = 4; d <= 32; d <<= 1) sm += __shfl_xor(sm, d);
  if (sub == 0) aw[wv][j] = e / sm;
  __syncthreads();
#pragma unroll
  for (int ci = 0; ci < DOUT / 64; ++ci) {
    int c = lane + (ci << 6);
    float o = 0.f;
#pragma unroll
    for (int jj = 0; jj < 16; ++jj)
      o += aw[wv][jj] * vp[(size_t)sw[wv][jj] * DOUT + c];
    size_t oi = (size_t)t * DOUT + c;
    xout[oi] = fmaxf(xout[oi] + o, 0.f);   // + skip (s), then ReLU
  }
}

// ---------------------------------------------------------------- Pool + head
__global__ void zero_kernel(float* g) { g[blockIdx.x * 256 + threadIdx.x] = 0.f; }

__global__ __launch_bounds__(256) void pool_kernel(const float* __restrict__ x3,
                                                   float* __restrict__ g) {
  int b = blockIdx.y, c = threadIdx.x;
  int p0 = blockIdx.x * 256;
  float m = 0.f;
  for (int p = p0; p < p0 + 256; ++p)
    m = fmaxf(m, x3[((size_t)b * NPTS + p) * 256 + c]);
  atomicMax((int*)&g[b * 256 + c], __float_as_int(m));  // valid: values >= 0
}

__global__ __launch_bounds__(256) void head_kernel(const float* __restrict__ g,
    const float* __restrict__ w1, const float* __restrict__ b1,
    const float* __restrict__ w2, const float* __restrict__ b2,
    const float* __restrict__ w3, const float* __restrict__ b3,
    float* __restrict__ out) {
  __shared__ float gb[256], h1[512], h2[256], lg[10];
  int b = blockIdx.x, t = threadIdx.x;
  gb[t] = g[b * 256 + t];
  __syncthreads();
#pragma unroll
  for (int half = 0; half < 2; ++half) {
    int c = t + half * 256;
    float a = b1[c];
    for (int kk = 0; kk < 256; ++kk) a += gb[kk] * w1[kk * 512 + c];
    h1[c] = fmaxf(a, 0.f);
  }
  __syncthreads();
  {
    float a = b2[t];
    for (int kk = 0; kk < 512; ++kk) a += h1[kk] * w2[kk * 256 + t];
    h2[t] = fmaxf(a, 0.f);
  }
  __syncthreads();
  if (t < 10) {
    float a = b3[t];
    for (int kk = 0; kk < 256; ++kk) a += h2[kk] * w3[kk * 10 + t];
    lg[t] = a;
  }
  __syncthreads();
  if (t < 10) {
    float mx = lg[0];
#pragma unroll
    for (int i = 1; i < 10; ++i) mx = fmaxf(mx, lg[i]);
    float s = 0.f;
#pragma unroll
    for (int i = 0; i < 10; ++i) s += expf(lg[i] - mx);
    out[b * 10 + t] = lg[t] - mx - logf(s);
  }
}

// ---------------------------------------------------------------- launch
extern "C" void kernel_launch(void* const* d_in, const int* in_sizes, int n_in,
                              void* d_out, int out_size, void* d_ws, size_t ws_size,
                              hipStream_t stream) {
  const float* pos = (const float*)d_in[0];
  const float* W[3][4]; const float* Bb[3][4];
  for (int l = 0; l < 3; ++l)
    for (int nm = 0; nm < 4; ++nm) {           // order q,k,v,s
      W[l][nm]  = (const float*)d_in[1 + l * 8 + nm * 2];
      Bb[l][nm] = (const float*)d_in[1 + l * 8 + nm * 2 + 1];
    }
  const float* fc1w = (const float*)d_in[25]; const float* fc1b = (const float*)d_in[26];
  const float* fc2w = (const float*)d_in[27]; const float* fc2b = (const float*)d_in[28];
  const float* fc3w = (const float*)d_in[29]; const float* fc3b = (const float*)d_in[30];

  int*   idxb  = (int*)d_ws;
  float* fbase = (float*)((char*)d_ws + (size_t)MTOT * NBR * 4);
  float* qb = fbase;
  float* kb = qb + (size_t)MTOT * 256;
  float* vb = kb + (size_t)MTOT * 256;
  float* x1 = vb + (size_t)MTOT * 256;
  float* x2 = x1 + (size_t)MTOT * 64;
  float* x3 = x2 + (size_t)MTOT * 128;
  float* g  = x3 + (size_t)MTOT * 256;

  knn_kernel<<<dim3(16, 8), 256, 0, stream>>>(pos, idxb);

  // layer 1: din=3, dout=64
  gemm_bias<<<dim3(512, 1), 256, 0, stream>>>(pos, W[0][0], Bb[0][0], qb, 3, 64);
  gemm_bias<<<dim3(512, 1), 256, 0, stream>>>(pos, W[0][1], Bb[0][1], kb, 3, 64);
  gemm_bias<<<dim3(512, 1), 256, 0, stream>>>(pos, W[0][2], Bb[0][2], vb, 3, 64);
  gemm_bias<<<dim3(512, 1), 256, 0, stream>>>(pos, W[0][3], Bb[0][3], x1, 3, 64);
  attn_kernel<64><<<MTOT / 4, 256, 0, stream>>>(qb, kb, vb, idxb, x1);

  // layer 2: din=64, dout=128
  gemm_bias<<<dim3(512, 2), 256, 0, stream>>>(x1, W[1][0], Bb[1][0], qb, 64, 128);
  gemm_bias<<<dim3(512, 2), 256, 0, stream>>>(x1, W[1][1], Bb[1][1], kb, 64, 128);
  gemm_bias<<<dim3(512, 2), 256, 0, stream>>>(x1, W[1][2], Bb[1][2], vb, 64, 128);
  gemm_bias<<<dim3(512, 2), 256, 0, stream>>>(x1, W[1][3], Bb[1][3], x2, 64, 128);
  attn_kernel<128><<<MTOT / 4, 256, 0, stream>>>(qb, kb, vb, idxb, x2);

  // layer 3: din=128, dout=256
  gemm_bias<<<dim3(512, 4), 256, 0, stream>>>(x2, W[2][0], Bb[2][0], qb, 128, 256);
  gemm_bias<<<dim3(512, 4), 256, 0, stream>>>(x2, W[2][1], Bb[2][1], kb, 128, 256);
  gemm_bias<<<dim3(512, 4), 256, 0, stream>>>(x2, W[2][2], Bb[2][2], vb, 128, 256);
  gemm_bias<<<dim3(512, 4), 256, 0, stream>>>(x2, W[2][3], Bb[2][3], x3, 128, 256);
  attn_kernel<256><<<MTOT / 4, 256, 0, stream>>>(qb, kb, vb, idxb, x3);

  // global max pool + MLP head
  zero_kernel<<<8, 256, 0, stream>>>(g);
  pool_kernel<<<dim3(16, 8), 256, 0, stream>>>(x3, g);
  head_kernel<<<8, 256, 0, stream>>>(g, fc1w, fc1b, fc2w, fc2b, fc3w, fc3b,
                                     (float*)d_out);
}

// Round 2
// 676.867 us; speedup vs baseline: 2.8303x; 2.8303x over previous
//
#include <hip/hip_runtime.h>
#include <math.h>

#define BATCH 8
#define NPTS  4096
#define NBR   16
#define MTOT  (BATCH * NPTS)   // 32768

#define KNN_BINS 4096          // top-12 bits of order-flipped float
#define KNN_CAP  64            // max pivot-bin members handled exactly

// ---------------------------------------------------------------- prep
__global__ __launch_bounds__(256) void prep_pos4(const float* __restrict__ pos,
                                                 float4* __restrict__ pos4) {
  int i = blockIdx.x * 256 + threadIdx.x;            // 0..MTOT-1
  float x = pos[i * 3 + 0], y = pos[i * 3 + 1], z = pos[i * 3 + 2];
  pos4[i] = make_float4(x, y, z, x * x + y * y + z * z);
}

// ---------------------------------------------------------------- KNN
// One block = one target point. 256 threads x 16 candidates each.
// Branchless keys -> 4096-bin LDS histogram over top-12 bits -> pivot bin
// containing the 16th smallest -> below-pivot emitted directly, pivot-bin
// members resolved exactly by (key, idx) min-extraction (wave 0).
// Output order is arbitrary: downstream softmax/gather is permutation-invariant.
__global__ __launch_bounds__(256) void knn_kernel(const float4* __restrict__ pos4,
                                                  int* __restrict__ idxout) {
  __shared__ unsigned hist[KNN_BINS];
  __shared__ unsigned tsum[256];
  __shared__ unsigned long long cand[KNN_CAP];
  __shared__ unsigned nPiv, nOut, s_pivot, s_c0;

  int t = blockIdx.x;                 // global target
  int b = t >> 12;
  int p = t & (NPTS - 1);
  const float4* base = pos4 + ((size_t)b << 12);
  float4 me = base[p];

  int tid = threadIdx.x;
#pragma unroll
  for (int i = 0; i < KNN_BINS / 256; ++i) hist[tid + i * 256] = 0;
  if (tid == 0) { nPiv = 0; nOut = 0; }
  __syncthreads();

  unsigned key[16];
#pragma unroll
  for (int j = 0; j < 16; ++j) {
    int q = tid + j * 256;
    float4 o = base[q];
    float d2 = me.w + o.w - 2.f * (me.x * o.x + me.y * o.y + me.z * o.z);
    unsigned u = __float_as_uint(d2);
    unsigned k2 = u ^ (unsigned)(((int)u >> 31) | 0x80000000);  // order-preserving flip
    key[j] = (q == p) ? 0xFFFFFFFFu : k2;                       // exclude self
    atomicAdd(&hist[key[j] >> 20], 1u);
  }
  __syncthreads();

  // hierarchical cumulative search for the bin where cumcount crosses 16
  unsigned s = 0;
#pragma unroll
  for (int i = 0; i < 16; ++i) s += hist[tid * 16 + i];
  tsum[tid] = s;
  __syncthreads();

  if (tid < 64) {
    unsigned g = tsum[tid * 4] + tsum[tid * 4 + 1] + tsum[tid * 4 + 2] + tsum[tid * 4 + 3];
    unsigned c = g;
#pragma unroll
    for (int d = 1; d < 64; d <<= 1) {
      unsigned x = __shfl_up(c, d);
      if (tid >= d) c += x;
    }
    unsigned long long m = __ballot(c >= NBR);
    int L = __ffsll((unsigned long long)m) - 1;
    unsigned cumL = __shfl(c, L);
    unsigned gL = __shfl(g, L);
    if (tid == 0) {
      unsigned c0 = cumL - gL;        // count strictly before lane L's group
      int T = 4 * L;
      while (c0 + tsum[T] < NBR) { c0 += tsum[T]; ++T; }
      int bin = T * 16;
      while (c0 + hist[bin] < NBR) { c0 += hist[bin]; ++bin; }
      s_pivot = (unsigned)bin; s_c0 = c0;
    }
  }
  __syncthreads();

  unsigned pivot = s_pivot, c0 = s_c0;
  int* op = idxout + (size_t)t * NBR;
#pragma unroll
  for (int j = 0; j < 16; ++j) {
    unsigned bin = key[j] >> 20;
    if (bin < pivot) {
      unsigned slot = atomicAdd(&nOut, 1u);
      op[slot] = tid + j * 256;
    } else if (bin == pivot) {
      unsigned slot = atomicAdd(&nPiv, 1u);
      if (slot < KNN_CAP)
        cand[slot] = ((unsigned long long)key[j] << 32) | (unsigned)(tid + j * 256);
    }
  }
  __syncthreads();

  if (tid < 64) {
    int n = (int)(nPiv < KNN_CAP ? nPiv : KNN_CAP);
    int need = NBR - (int)c0;
    unsigned long long val = (tid < n) ? cand[tid] : ~0ULL;
    for (int it = 0; it < need; ++it) {
      unsigned long long m = val;
#pragma unroll
      for (int d = 1; d < 64; d <<= 1) {
        unsigned long long o = __shfl_xor(m, d);
        m = (o < m) ? o : m;
      }
      if (val == m) {                 // unique winner (idx embedded in key)
        op[c0 + it] = (int)(m & 0xFFFFFFFFu);
        val = ~0ULL;
      }
    }
  }
}

// ---------------------------------------------------------------- GEMM (fp32)
// out[M,N] = X[M,K] @ W[K,N] + bias.  64x64 tile, BK=16, 256 thr, 4x4 micro.
__global__ __launch_bounds__(256) void gemm_bias(const float* __restrict__ X,
                                                 const float* __restrict__ W,
                                                 const float* __restrict__ bias,
                                                 float* __restrict__ out,
                                                 int K, int N) {
  __shared__ float As[16][68];
  __shared__ float Bs[16][64];
  int tid = threadIdx.x;
  int bm = blockIdx.x * 64;
  int bn = blockIdx.y * 64;
  int tr = tid >> 4, tc = tid & 15;
  float acc[4][4] = {{0.f}};
  for (int k0 = 0; k0 < K; k0 += 16) {
#pragma unroll
    for (int i = 0; i < 4; ++i) {
      int rr = (tid >> 4) + (i << 4);
      int kk = tid & 15;
      As[kk][rr] = (k0 + kk < K) ? X[(size_t)(bm + rr) * K + (k0 + kk)] : 0.f;
    }
#pragma unroll
    for (int i = 0; i < 4; ++i) {
      int kk = (tid >> 6) + (i << 2);
      int c  = tid & 63;
      Bs[kk][c] = (k0 + kk < K) ? W[(size_t)(k0 + kk) * N + (bn + c)] : 0.f;
    }
    __syncthreads();
#pragma unroll
    for (int kk = 0; kk < 16; ++kk) {
      float4 av = *(const float4*)&As[kk][tr << 2];
      float4 bv = *(const float4*)&Bs[kk][tc << 2];
      float a_[4] = {av.x, av.y, av.z, av.w};
      float b_[4] = {bv.x, bv.y, bv.z, bv.w};
#pragma unroll
      for (int i = 0; i < 4; ++i)
#pragma unroll
        for (int j = 0; j < 4; ++j)
          acc[i][j] += a_[i] * b_[j];
    }
    __syncthreads();
  }
  float4 bsv = *(const float4*)&bias[bn + (tc << 2)];
  float bb[4] = {bsv.x, bsv.y, bsv.z, bsv.w};
#pragma unroll
  for (int i = 0; i < 4; ++i) {
    float4 o;
    o.x = acc[i][0] + bb[0];
    o.y = acc[i][1] + bb[1];
    o.z = acc[i][2] + bb[2];
    o.w = acc[i][3] + bb[3];
    *(float4*)&out[(size_t)(bm + (tr << 2) + i) * N + bn + (tc << 2)] = o;
  }
}

// ---------------------------------------------------------------- Attention
template <int DOUT>
__global__ __launch_bounds__(256) void attn_kernel(const float* __restrict__ qp,
                                                   const float* __restrict__ kp,
                                                   const float* __restrict__ vp,
                                                   const int* __restrict__ idx,
                                                   float* __restrict__ xout) {
  __shared__ float qrow[4][DOUT];
  __shared__ float aw[4][16];
  __shared__ int   sw[4][16];
  int lane = threadIdx.x & 63, wv = threadIdx.x >> 6;
  int t = blockIdx.x * 4 + wv;
  int b = t >> 12;
  if (lane < 16) sw[wv][lane] = (b << 12) + idx[t * 16 + lane];
  constexpr int F = DOUT / 4;
  if (lane < F)
    ((float4*)qrow[wv])[lane] = ((const float4*)(qp + (size_t)t * DOUT))[lane];
  __syncthreads();
  int j = lane >> 2, sub = lane & 3;
  int src = sw[wv][j];
  const float4* krow = (const float4*)(kp + (size_t)src * DOUT);
  const float4* q4 = (const float4*)qrow[wv];
  float acc = 0.f;
#pragma unroll
  for (int f = sub; f < F; f += 4) {
    float4 kk = krow[f], qq = q4[f];
    acc += qq.x * kk.x + qq.y * kk.y + qq.z * kk.z + qq.w * kk.w;
  }
  acc += __shfl_xor(acc, 1);
  acc += __shfl_xor(acc, 2);
  const float scale = (DOUT == 64) ? 0.125f
                    : (DOUT == 128) ? 0.08838834764831843f : 0.0625f;
  float logit = acc * scale;
  float mx = logit;
#pragma unroll
  for (int d = 4; d <= 32; d <<= 1) mx = fmaxf(mx, __shfl_xor(mx, d));
  float e = expf(logit - mx);
  float sm = e;
#pragma unroll
  for (int d = 4; d <= 32; d <<= 1) sm += __shfl_xor(sm, d);
  if (sub == 0) aw[wv][j] = e / sm;
  __syncthreads();
#pragma unroll
  for (int ci = 0; ci < DOUT / 64; ++ci) {
    int c = lane + (ci << 6);
    float o = 0.f;
#pragma unroll
    for (int jj = 0; jj < 16; ++jj)
      o += aw[wv][jj] * vp[(size_t)sw[wv][jj] * DOUT + c];
    size_t oi = (size_t)t * DOUT + c;
    xout[oi] = fmaxf(xout[oi] + o, 0.f);
  }
}

// ---------------------------------------------------------------- Pool + head
__global__ void zero_kernel(float* g) { g[blockIdx.x * 256 + threadIdx.x] = 0.f; }

__global__ __launch_bounds__(256) void pool_kernel(const float* __restrict__ x3,
                                                   float* __restrict__ g) {
  int b = blockIdx.y, c = threadIdx.x;
  int p0 = blockIdx.x * 256;
  float m = 0.f;
  for (int p = p0; p < p0 + 256; ++p)
    m = fmaxf(m, x3[((size_t)b * NPTS + p) * 256 + c]);
  atomicMax((int*)&g[b * 256 + c], __float_as_int(m));
}

__global__ __launch_bounds__(256) void head_kernel(const float* __restrict__ g,
    const float* __restrict__ w1, const float* __restrict__ b1,
    const float* __restrict__ w2, const float* __restrict__ b2,
    const float* __restrict__ w3, const float* __restrict__ b3,
    float* __restrict__ out) {
  __shared__ float gb[256], h1[512], h2[256], lg[10];
  int b = blockIdx.x, t = threadIdx.x;
  gb[t] = g[b * 256 + t];
  __syncthreads();
#pragma unroll
  for (int half = 0; half < 2; ++half) {
    int c = t + half * 256;
    float a = b1[c];
    for (int kk = 0; kk < 256; ++kk) a += gb[kk] * w1[kk * 512 + c];
    h1[c] = fmaxf(a, 0.f);
  }
  __syncthreads();
  {
    float a = b2[t];
    for (int kk = 0; kk < 512; ++kk) a += h1[kk] * w2[kk * 256 + t];
    h2[t] = fmaxf(a, 0.f);
  }
  __syncthreads();
  if (t < 10) {
    float a = b3[t];
    for (int kk = 0; kk < 256; ++kk) a += h2[kk] * w3[kk * 10 + t];
    lg[t] = a;
  }
  __syncthreads();
  if (t < 10) {
    float mx = lg[0];
#pragma unroll
    for (int i = 1; i < 10; ++i) mx = fmaxf(mx, lg[i]);
    float s = 0.f;
#pragma unroll
    for (int i = 0; i < 10; ++i) s += expf(lg[i] - mx);
    out[b * 10 + t] = lg[t] - mx - logf(s);
  }
}

// ---------------------------------------------------------------- launch
extern "C" void kernel_launch(void* const* d_in, const int* in_sizes, int n_in,
                              void* d_out, int out_size, void* d_ws, size_t ws_size,
                              hipStream_t stream) {
  const float* pos = (const float*)d_in[0];
  const float* W[3][4]; const float* Bb[3][4];
  for (int l = 0; l < 3; ++l)
    for (int nm = 0; nm < 4; ++nm) {           // order q,k,v,s
      W[l][nm]  = (const float*)d_in[1 + l * 8 + nm * 2];
      Bb[l][nm] = (const float*)d_in[1 + l * 8 + nm * 2 + 1];
    }
  const float* fc1w = (const float*)d_in[25]; const float* fc1b = (const float*)d_in[26];
  const float* fc2w = (const float*)d_in[27]; const float* fc2b = (const float*)d_in[28];
  const float* fc3w = (const float*)d_in[29]; const float* fc3b = (const float*)d_in[30];

  int*   idxb  = (int*)d_ws;
  float* fbase = (float*)((char*)d_ws + (size_t)MTOT * NBR * 4);
  float* qb = fbase;
  float* kb = qb + (size_t)MTOT * 256;
  float* vb = kb + (size_t)MTOT * 256;
  float* x1 = vb + (size_t)MTOT * 256;
  float* x2 = x1 + (size_t)MTOT * 64;
  float* x3 = x2 + (size_t)MTOT * 128;
  float* g  = x3 + (size_t)MTOT * 256;
  float4* pos4 = (float4*)(g + BATCH * 256);

  prep_pos4<<<MTOT / 256, 256, 0, stream>>>(pos, pos4);
  knn_kernel<<<MTOT, 256, 0, stream>>>(pos4, idxb);

  // layer 1: din=3, dout=64
  gemm_bias<<<dim3(512, 1), 256, 0, stream>>>(pos, W[0][0], Bb[0][0], qb, 3, 64);
  gemm_bias<<<dim3(512, 1), 256, 0, stream>>>(pos, W[0][1], Bb[0][1], kb, 3, 64);
  gemm_bias<<<dim3(512, 1), 256, 0, stream>>>(pos, W[0][2], Bb[0][2], vb, 3, 64);
  gemm_bias<<<dim3(512, 1), 256, 0, stream>>>(pos, W[0][3], Bb[0][3], x1, 3, 64);
  attn_kernel<64><<<MTOT / 4, 256, 0, stream>>>(qb, kb, vb, idxb, x1);

  // layer 2: din=64, dout=128
  gemm_bias<<<dim3(512, 2), 256, 0, stream>>>(x1, W[1][0], Bb[1][0], qb, 64, 128);
  gemm_bias<<<dim3(512, 2), 256, 0, stream>>>(x1, W[1][1], Bb[1][1], kb, 64, 128);
  gemm_bias<<<dim3(512, 2), 256, 0, stream>>>(x1, W[1][2], Bb[1][2], vb, 64, 128);
  gemm_bias<<<dim3(512, 2), 256, 0, stream>>>(x1, W[1][3], Bb[1][3], x2, 64, 128);
  attn_kernel<128><<<MTOT / 4, 256, 0, stream>>>(qb, kb, vb, idxb, x2);

  // layer 3: din=128, dout=256
  gemm_bias<<<dim3(512, 4), 256, 0, stream>>>(x2, W[2][0], Bb[2][0], qb, 128, 256);
  gemm_bias<<<dim3(512, 4), 256, 0, stream>>>(x2, W[2][1], Bb[2][1], kb, 128, 256);
  gemm_bias<<<dim3(512, 4), 256, 0, stream>>>(x2, W[2][2], Bb[2][2], vb, 128, 256);
  gemm_bias<<<dim3(512, 4), 256, 0, stream>>>(x2, W[2][3], Bb[2][3], x3, 128, 256);
  attn_kernel<256><<<MTOT / 4, 256, 0, stream>>>(qb, kb, vb, idxb, x3);

  // global max pool + MLP head
  zero_kernel<<<8, 256, 0, stream>>>(g);
  pool_kernel<<<dim3(16, 8), 256, 0, stream>>>(x3, g);
  head_kernel<<<8, 256, 0, stream>>>(g, fc1w, fc1b, fc2w, fc2b, fc3w, fc3b,
                                     (float*)d_out);
}

// Round 3
// 648.342 us; speedup vs baseline: 2.9548x; 1.0440x over previous
//
#include <hip/hip_runtime.h>
#include <math.h>

#define BATCH 8
#define NPTS  4096
#define NBR   16
#define MTOT  (BATCH * NPTS)   // 32768

#define KNN_BINS 4096          // top-12 bits of order-flipped float
#define KNN_CAP  64            // max pivot-bin members handled exactly

// ---------------------------------------------------------------- prep
__global__ __launch_bounds__(256) void prep_pos4(const float* __restrict__ pos,
                                                 float4* __restrict__ pos4) {
  int i = blockIdx.x * 256 + threadIdx.x;            // 0..MTOT-1
  float x = pos[i * 3 + 0], y = pos[i * 3 + 1], z = pos[i * 3 + 2];
  pos4[i] = make_float4(x, y, z, x * x + y * y + z * z);
}

// ---------------------------------------------------------------- KNN
// One block = one target point. 256 threads x 16 candidates each.
// Branchless keys -> 4096-bin LDS histogram over top-12 bits -> pivot bin
// containing the 16th smallest -> below-pivot emitted directly, pivot-bin
// members resolved exactly by (key, idx) min-extraction (wave 0).
// Output order is arbitrary: downstream softmax/gather is permutation-invariant.
__global__ __launch_bounds__(256) void knn_kernel(const float4* __restrict__ pos4,
                                                  int* __restrict__ idxout) {
  __shared__ unsigned hist[KNN_BINS];
  __shared__ unsigned tsum[256];
  __shared__ unsigned long long cand[KNN_CAP];
  __shared__ unsigned nPiv, nOut, s_pivot, s_c0;

  int t = blockIdx.x;                 // global target
  int b = t >> 12;
  int p = t & (NPTS - 1);
  const float4* base = pos4 + ((size_t)b << 12);
  float4 me = base[p];

  int tid = threadIdx.x;
#pragma unroll
  for (int i = 0; i < KNN_BINS / 256; ++i) hist[tid + i * 256] = 0;
  if (tid == 0) { nPiv = 0; nOut = 0; }
  __syncthreads();

  unsigned key[16];
#pragma unroll
  for (int j = 0; j < 16; ++j) {
    int q = tid + j * 256;
    float4 o = base[q];
    float d2 = me.w + o.w - 2.f * (me.x * o.x + me.y * o.y + me.z * o.z);
    unsigned u = __float_as_uint(d2);
    unsigned k2 = u ^ (unsigned)(((int)u >> 31) | 0x80000000);  // order-preserving flip
    key[j] = (q == p) ? 0xFFFFFFFFu : k2;                       // exclude self
    atomicAdd(&hist[key[j] >> 20], 1u);
  }
  __syncthreads();

  // hierarchical cumulative search for the bin where cumcount crosses 16
  unsigned s = 0;
#pragma unroll
  for (int i = 0; i < 16; ++i) s += hist[tid * 16 + i];
  tsum[tid] = s;
  __syncthreads();

  if (tid < 64) {
    unsigned g = tsum[tid * 4] + tsum[tid * 4 + 1] + tsum[tid * 4 + 2] + tsum[tid * 4 + 3];
    unsigned c = g;
#pragma unroll
    for (int d = 1; d < 64; d <<= 1) {
      unsigned x = __shfl_up(c, d);
      if (tid >= d) c += x;
    }
    unsigned long long m = __ballot(c >= NBR);
    int L = __ffsll((unsigned long long)m) - 1;
    unsigned cumL = __shfl(c, L);
    unsigned gL = __shfl(g, L);
    if (tid == 0) {
      unsigned c0 = cumL - gL;        // count strictly before lane L's group
      int T = 4 * L;
      while (c0 + tsum[T] < NBR) { c0 += tsum[T]; ++T; }
      int bin = T * 16;
      while (c0 + hist[bin] < NBR) { c0 += hist[bin]; ++bin; }
      s_pivot = (unsigned)bin; s_c0 = c0;
    }
  }
  __syncthreads();

  unsigned pivot = s_pivot, c0 = s_c0;
  int* op = idxout + (size_t)t * NBR;
#pragma unroll
  for (int j = 0; j < 16; ++j) {
    unsigned bin = key[j] >> 20;
    if (bin < pivot) {
      unsigned slot = atomicAdd(&nOut, 1u);
      op[slot] = tid + j * 256;
    } else if (bin == pivot) {
      unsigned slot = atomicAdd(&nPiv, 1u);
      if (slot < KNN_CAP)
        cand[slot] = ((unsigned long long)key[j] << 32) | (unsigned)(tid + j * 256);
    }
  }
  __syncthreads();

  if (tid < 64) {
    int n = (int)(nPiv < KNN_CAP ? nPiv : KNN_CAP);
    int need = NBR - (int)c0;
    unsigned long long val = (tid < n) ? cand[tid] : ~0ULL;
    for (int it = 0; it < need; ++it) {
      unsigned long long m = val;
#pragma unroll
      for (int d = 1; d < 64; d <<= 1) {
        unsigned long long o = __shfl_xor(m, d);
        m = (o < m) ? o : m;
      }
      if (val == m) {
        op[c0 + it] = (int)(m & 0xFFFFFFFFu);
        val = ~0ULL;
      }
    }
  }
}

// ---------------------------------------------------------------- GEMM (fp32)
__global__ __launch_bounds__(256) void gemm_bias(const float* __restrict__ X,
                                                 const float* __restrict__ W,
                                                 const float* __restrict__ bias,
                                                 float* __restrict__ out,
                                                 int K, int N) {
  __shared__ float As[16][68];
  __shared__ float Bs[16][64];
  int tid = threadIdx.x;
  int bm = blockIdx.x * 64;
  int bn = blockIdx.y * 64;
  int tr = tid >> 4, tc = tid & 15;
  float acc[4][4] = {{0.f}};
  for (int k0 = 0; k0 < K; k0 += 16) {
#pragma unroll
    for (int i = 0; i < 4; ++i) {
      int rr = (tid >> 4) + (i << 4);
      int kk = tid & 15;
      As[kk][rr] = (k0 + kk < K) ? X[(size_t)(bm + rr) * K + (k0 + kk)] : 0.f;
    }
#pragma unroll
    for (int i = 0; i < 4; ++i) {
      int kk = (tid >> 6) + (i << 2);
      int c  = tid & 63;
      Bs[kk][c] = (k0 + kk < K) ? W[(size_t)(k0 + kk) * N + (bn + c)] : 0.f;
    }
    __syncthreads();
#pragma unroll
    for (int kk = 0; kk < 16; ++kk) {
      float4 av = *(const float4*)&As[kk][tr << 2];
      float4 bv = *(const float4*)&Bs[kk][tc << 2];
      float a_[4] = {av.x, av.y, av.z, av.w};
      float b_[4] = {bv.x, bv.y, bv.z, bv.w};
#pragma unroll
      for (int i = 0; i < 4; ++i)
#pragma unroll
        for (int j = 0; j < 4; ++j)
          acc[i][j] += a_[i] * b_[j];
    }
    __syncthreads();
  }
  float4 bsv = *(const float4*)&bias[bn + (tc << 2)];
  float bb[4] = {bsv.x, bsv.y, bsv.z, bsv.w};
#pragma unroll
  for (int i = 0; i < 4; ++i) {
    float4 o;
    o.x = acc[i][0] + bb[0];
    o.y = acc[i][1] + bb[1];
    o.z = acc[i][2] + bb[2];
    o.w = acc[i][3] + bb[3];
    *(float4*)&out[(size_t)(bm + (tr << 2) + i) * N + bn + (tc << 2)] = o;
  }
}

// ---------------------------------------------------------------- Attention
// 4 targets per WAVE, one (target, neighbor) pair per lane. Full-row dots for
// logits (64 indep float4 loads/lane in flight), pure-shuffle softmax over the
// 16 lanes of each target group, then lanes re-map to (target, channel-slice)
// for PV with shfl-broadcast weights. One barrier per block (q/idx staging).
template <int DOUT>
__global__ __launch_bounds__(256) void attn_kernel(const float* __restrict__ qp,
                                                   const float* __restrict__ kp,
                                                   const float* __restrict__ vp,
                                                   const int* __restrict__ idx,
                                                   float* __restrict__ xout) {
  constexpr int F  = DOUT / 4;    // float4 per row
  constexpr int QF = DOUT / 64;   // float4 per lane in PV
  __shared__ float4 qs[4][4][F + 1];   // [wave][tgt][f] padded: row stride F+1
  __shared__ int    ss[4][64];         // [wave][tgt*16 + j]
  int lane = threadIdx.x & 63, wv = threadIdx.x >> 6;
  int t0 = blockIdx.x * 16 + wv * 4;          // first of this wave's 4 targets
  int bofs = (t0 >> 12) << 12;                // batch row offset
  int tt = lane >> 4, jj = lane & 15;         // (target-in-wave, neighbor)
  int src = bofs + idx[(t0 + tt) * 16 + jj];  // coalesced 64-int read
  ss[wv][lane] = src;
  const float4* qp4 = (const float4*)qp;
#pragma unroll
  for (int i = 0; i < F / 16; ++i) {          // q rows of 4 targets contiguous
    int g = lane + 64 * i;
    qs[wv][g / F][g % F] = qp4[(size_t)t0 * F + g];
  }
  __syncthreads();

  // ---- logits: full-row dot per lane
  const float4* krow = (const float4*)(kp + (size_t)src * DOUT);
  float acc = 0.f;
#pragma unroll
  for (int f = 0; f < F; ++f) {
    float4 kk = krow[f], qq = qs[wv][tt][f];
    acc += qq.x * kk.x + qq.y * kk.y + qq.z * kk.z + qq.w * kk.w;
  }
  const float scale = (DOUT == 64) ? 0.125f
                    : (DOUT == 128) ? 0.08838834764831843f : 0.0625f;
  float logit = acc * scale;
  float mx = logit;
#pragma unroll
  for (int d = 1; d <= 8; d <<= 1) mx = fmaxf(mx, __shfl_xor(mx, d));
  float e = expf(logit - mx);
  float sm = e;
#pragma unroll
  for (int d = 1; d <= 8; d <<= 1) sm += __shfl_xor(sm, d);
  float a = e / sm;

  // ---- PV: lane -> (target tt, float4-slice jj, jj+16, ...)
  float4 o[QF];
#pragma unroll
  for (int u = 0; u < QF; ++u) o[u] = make_float4(0.f, 0.f, 0.f, 0.f);
  int gbase = lane & 48;
#pragma unroll
  for (int j = 0; j < 16; ++j) {
    float aj = __shfl(a, gbase | j);
    const float4* vrow = (const float4*)(vp + (size_t)ss[wv][gbase | j] * DOUT);
#pragma unroll
    for (int u = 0; u < QF; ++u) {
      float4 vv = vrow[jj + 16 * u];
      o[u].x += aj * vv.x; o[u].y += aj * vv.y;
      o[u].z += aj * vv.z; o[u].w += aj * vv.w;
    }
  }
  float4* xo4 = (float4*)xout;
#pragma unroll
  for (int u = 0; u < QF; ++u) {
    size_t oi = (size_t)(t0 + tt) * F + jj + 16 * u;
    float4 x4 = xo4[oi];
    float4 r;
    r.x = fmaxf(x4.x + o[u].x, 0.f);
    r.y = fmaxf(x4.y + o[u].y, 0.f);
    r.z = fmaxf(x4.z + o[u].z, 0.f);
    r.w = fmaxf(x4.w + o[u].w, 0.f);
    xo4[oi] = r;
  }
}

// ---------------------------------------------------------------- Pool + head
__global__ void zero_kernel(float* g) { g[blockIdx.x * 256 + threadIdx.x] = 0.f; }

__global__ __launch_bounds__(256) void pool_kernel(const float* __restrict__ x3,
                                                   float* __restrict__ g) {
  int b = blockIdx.y, c = threadIdx.x;
  int p0 = blockIdx.x * 256;
  float m = 0.f;
  for (int p = p0; p < p0 + 256; ++p)
    m = fmaxf(m, x3[((size_t)b * NPTS + p) * 256 + c]);
  atomicMax((int*)&g[b * 256 + c], __float_as_int(m));
}

__global__ __launch_bounds__(256) void head_kernel(const float* __restrict__ g,
    const float* __restrict__ w1, const float* __restrict__ b1,
    const float* __restrict__ w2, const float* __restrict__ b2,
    const float* __restrict__ w3, const float* __restrict__ b3,
    float* __restrict__ out) {
  __shared__ float gb[256], h1[512], h2[256], lg[10];
  int b = blockIdx.x, t = threadIdx.x;
  gb[t] = g[b * 256 + t];
  __syncthreads();
#pragma unroll
  for (int half = 0; half < 2; ++half) {
    int c = t + half * 256;
    float a = b1[c];
    for (int kk = 0; kk < 256; ++kk) a += gb[kk] * w1[kk * 512 + c];
    h1[c] = fmaxf(a, 0.f);
  }
  __syncthreads();
  {
    float a = b2[t];
    for (int kk = 0; kk < 512; ++kk) a += h1[kk] * w2[kk * 256 + t];
    h2[t] = fmaxf(a, 0.f);
  }
  __syncthreads();
  if (t < 10) {
    float a = b3[t];
    for (int kk = 0; kk < 256; ++kk) a += h2[kk] * w3[kk * 10 + t];
    lg[t] = a;
  }
  __syncthreads();
  if (t < 10) {
    float mx = lg[0];
#pragma unroll
    for (int i = 1; i < 10; ++i) mx = fmaxf(mx, lg[i]);
    float s = 0.f;
#pragma unroll
    for (int i = 0; i < 10; ++i) s += expf(lg[i] - mx);
    out[b * 10 + t] = lg[t] - mx - logf(s);
  }
}

// ---------------------------------------------------------------- launch
extern "C" void kernel_launch(void* const* d_in, const int* in_sizes, int n_in,
                              void* d_out, int out_size, void* d_ws, size_t ws_size,
                              hipStream_t stream) {
  const float* pos = (const float*)d_in[0];
  const float* W[3][4]; const float* Bb[3][4];
  for (int l = 0; l < 3; ++l)
    for (int nm = 0; nm < 4; ++nm) {           // order q,k,v,s
      W[l][nm]  = (const float*)d_in[1 + l * 8 + nm * 2];
      Bb[l][nm] = (const float*)d_in[1 + l * 8 + nm * 2 + 1];
    }
  const float* fc1w = (const float*)d_in[25]; const float* fc1b = (const float*)d_in[26];
  const float* fc2w = (const float*)d_in[27]; const float* fc2b = (const float*)d_in[28];
  const float* fc3w = (const float*)d_in[29]; const float* fc3b = (const float*)d_in[30];

  int*   idxb  = (int*)d_ws;
  float* fbase = (float*)((char*)d_ws + (size_t)MTOT * NBR * 4);
  float* qb = fbase;
  float* kb = qb + (size_t)MTOT * 256;
  float* vb = kb + (size_t)MTOT * 256;
  float* x1 = vb + (size_t)MTOT * 256;
  float* x2 = x1 + (size_t)MTOT * 64;
  float* x3 = x2 + (size_t)MTOT * 128;
  float* g  = x3 + (size_t)MTOT * 256;
  float4* pos4 = (float4*)(g + BATCH * 256);

  prep_pos4<<<MTOT / 256, 256, 0, stream>>>(pos, pos4);
  knn_kernel<<<MTOT, 256, 0, stream>>>(pos4, idxb);

  // layer 1: din=3, dout=64
  gemm_bias<<<dim3(512, 1), 256, 0, stream>>>(pos, W[0][0], Bb[0][0], qb, 3, 64);
  gemm_bias<<<dim3(512, 1), 256, 0, stream>>>(pos, W[0][1], Bb[0][1], kb, 3, 64);
  gemm_bias<<<dim3(512, 1), 256, 0, stream>>>(pos, W[0][2], Bb[0][2], vb, 3, 64);
  gemm_bias<<<dim3(512, 1), 256, 0, stream>>>(pos, W[0][3], Bb[0][3], x1, 3, 64);
  attn_kernel<64><<<MTOT / 16, 256, 0, stream>>>(qb, kb, vb, idxb, x1);

  // layer 2: din=64, dout=128
  gemm_bias<<<dim3(512, 2), 256, 0, stream>>>(x1, W[1][0], Bb[1][0], qb, 64, 128);
  gemm_bias<<<dim3(512, 2), 256, 0, stream>>>(x1, W[1][1], Bb[1][1], kb, 64, 128);
  gemm_bias<<<dim3(512, 2), 256, 0, stream>>>(x1, W[1][2], Bb[1][2], vb, 64, 128);
  gemm_bias<<<dim3(512, 2), 256, 0, stream>>>(x1, W[1][3], Bb[1][3], x2, 64, 128);
  attn_kernel<128><<<MTOT / 16, 256, 0, stream>>>(qb, kb, vb, idxb, x2);

  // layer 3: din=128, dout=256
  gemm_bias<<<dim3(512, 4), 256, 0, stream>>>(x2, W[2][0], Bb[2][0], qb, 128, 256);
  gemm_bias<<<dim3(512, 4), 256, 0, stream>>>(x2, W[2][1], Bb[2][1], kb, 128, 256);
  gemm_bias<<<dim3(512, 4), 256, 0, stream>>>(x2, W[2][2], Bb[2][2], vb, 128, 256);
  gemm_bias<<<dim3(512, 4), 256, 0, stream>>>(x2, W[2][3], Bb[2][3], x3, 128, 256);
  attn_kernel<256><<<MTOT / 16, 256, 0, stream>>>(qb, kb, vb, idxb, x3);

  // global max pool + MLP head
  zero_kernel<<<8, 256, 0, stream>>>(g);
  pool_kernel<<<dim3(16, 8), 256, 0, stream>>>(x3, g);
  head_kernel<<<8, 256, 0, stream>>>(g, fc1w, fc1b, fc2w, fc2b, fc3w, fc3b,
                                     (float*)d_out);
}

// Round 4
// 628.465 us; speedup vs baseline: 3.0482x; 1.0316x over previous
//
#include <hip/hip_runtime.h>
#include <math.h>

#define BATCH 8
#define NPTS  4096
#define NBR   16
#define MTOT  (BATCH * NPTS)   // 32768

#define KNN_BINS 4096          // top-12 bits of order-flipped float
#define KNN_CAP  64            // max pivot-bin members handled exactly

__device__ inline unsigned short f2bf(float f) {   // RNE bf16 bits
  unsigned u = __float_as_uint(f);
  return (unsigned short)((u + 0x7FFFu + ((u >> 16) & 1u)) >> 16);
}
__device__ inline float2 bf2(unsigned u) {         // two bf16 -> two floats
  return make_float2(__uint_as_float(u << 16), __uint_as_float(u & 0xFFFF0000u));
}

// ---------------------------------------------------------------- prep
__global__ __launch_bounds__(256) void prep_pos4(const float* __restrict__ pos,
                                                 float4* __restrict__ pos4) {
  int i = blockIdx.x * 256 + threadIdx.x;
  float x = pos[i * 3 + 0], y = pos[i * 3 + 1], z = pos[i * 3 + 2];
  pos4[i] = make_float4(x, y, z, x * x + y * y + z * z);
}

// ---------------------------------------------------------------- KNN
// One block = one target. Histogram select with SWIZZLED layout:
// bin b lives at hist[(b&15)*256 + (b>>4)] so the per-thread 16-bin sweep
// reads stride-256 (bank = tid%32, conflict-free). Prefix via wave shfl scan.
__global__ __launch_bounds__(256) void knn_kernel(const float4* __restrict__ pos4,
                                                  int* __restrict__ idxout) {
  __shared__ unsigned hist[KNN_BINS];
  __shared__ unsigned wsum[4];
  __shared__ unsigned long long cand[KNN_CAP];
  __shared__ unsigned nPiv, nOut, s_pivot, s_c0;

  int t = blockIdx.x;
  int b = t >> 12;
  int p = t & (NPTS - 1);
  const float4* base = pos4 + ((size_t)b << 12);
  float4 me = base[p];

  int tid = threadIdx.x;
  int lane = tid & 63, wv = tid >> 6;
#pragma unroll
  for (int i = 0; i < KNN_BINS / 256; ++i) hist[tid + i * 256] = 0;
  if (tid == 0) { nPiv = 0; nOut = 0; }
  __syncthreads();

  unsigned key[16];
#pragma unroll
  for (int j = 0; j < 16; ++j) {
    int q = tid + j * 256;
    float4 o = base[q];
    float d2 = me.w + o.w - 2.f * (me.x * o.x + me.y * o.y + me.z * o.z);
    unsigned u = __float_as_uint(d2);
    unsigned k2 = u ^ (unsigned)(((int)u >> 31) | 0x80000000);
    key[j] = (q == p) ? 0xFFFFFFFFu : k2;
    // swizzled addr: ((bin&15)<<8) | (bin>>4), bin = key>>20
    atomicAdd(&hist[(((key[j] >> 20) & 15u) << 8) + (key[j] >> 24)], 1u);
  }
  __syncthreads();

  // per-thread count of its 16 contiguous bins [tid*16, tid*16+16)
  unsigned s = 0;
#pragma unroll
  for (int i = 0; i < 16; ++i) s += hist[i * 256 + tid];
  // inclusive wave scan
  unsigned c = s;
#pragma unroll
  for (int d = 1; d < 64; d <<= 1) {
    unsigned x = __shfl_up(c, d);
    if (lane >= d) c += x;
  }
  if (lane == 63) wsum[wv] = c;
  __syncthreads();
  unsigned off = 0;
#pragma unroll
  for (int w = 0; w < 4; ++w) off += (w < wv) ? wsum[w] : 0u;
  unsigned cum_incl = c + off;
  unsigned cum_excl = cum_incl - s;

  if (cum_excl < NBR && cum_incl >= NBR) {   // unique owner thread
    unsigned h[16];
#pragma unroll
    for (int i = 0; i < 16; ++i) h[i] = hist[i * 256 + tid];
    unsigned c0 = cum_excl; int bin = tid * 16; bool done = false;
#pragma unroll
    for (int i = 0; i < 16; ++i) {
      if (!done) {
        if (c0 + h[i] >= NBR) done = true;
        else { c0 += h[i]; ++bin; }
      }
    }
    s_pivot = (unsigned)bin; s_c0 = c0;
  }
  __syncthreads();

  unsigned pivot = s_pivot, c0 = s_c0;
  int* op = idxout + (size_t)t * NBR;
#pragma unroll
  for (int j = 0; j < 16; ++j) {
    unsigned bin = key[j] >> 20;
    if (bin < pivot) {
      unsigned slot = atomicAdd(&nOut, 1u);
      op[slot] = tid + j * 256;
    } else if (bin == pivot) {
      unsigned slot = atomicAdd(&nPiv, 1u);
      if (slot < KNN_CAP)
        cand[slot] = ((unsigned long long)key[j] << 32) | (unsigned)(tid + j * 256);
    }
  }
  __syncthreads();

  if (tid < 64) {
    int n = (int)(nPiv < KNN_CAP ? nPiv : KNN_CAP);
    int need = NBR - (int)c0;
    unsigned long long val = (tid < n) ? cand[tid] : ~0ULL;
    for (int it = 0; it < need; ++it) {
      unsigned long long m = val;
#pragma unroll
      for (int d = 1; d < 64; d <<= 1) {
        unsigned long long o = __shfl_xor(m, d);
        m = (o < m) ? o : m;
      }
      if (val == m) {
        op[c0 + it] = (int)(m & 0xFFFFFFFFu);
        val = ~0ULL;
      }
    }
  }
}

// ---------------------------------------------------------------- GEMM (fp32 out)
__global__ __launch_bounds__(256) void gemm_bias(const float* __restrict__ X,
                                                 const float* __restrict__ W,
                                                 const float* __restrict__ bias,
                                                 float* __restrict__ out,
                                                 int K, int N) {
  __shared__ float As[16][68];
  __shared__ float Bs[16][64];
  int tid = threadIdx.x;
  int bm = blockIdx.x * 64;
  int bn = blockIdx.y * 64;
  int tr = tid >> 4, tc = tid & 15;
  float acc[4][4] = {{0.f}};
  for (int k0 = 0; k0 < K; k0 += 16) {
#pragma unroll
    for (int i = 0; i < 4; ++i) {
      int rr = (tid >> 4) + (i << 4);
      int kk = tid & 15;
      As[kk][rr] = (k0 + kk < K) ? X[(size_t)(bm + rr) * K + (k0 + kk)] : 0.f;
    }
#pragma unroll
    for (int i = 0; i < 4; ++i) {
      int kk = (tid >> 6) + (i << 2);
      int c  = tid & 63;
      Bs[kk][c] = (k0 + kk < K) ? W[(size_t)(k0 + kk) * N + (bn + c)] : 0.f;
    }
    __syncthreads();
#pragma unroll
    for (int kk = 0; kk < 16; ++kk) {
      float4 av = *(const float4*)&As[kk][tr << 2];
      float4 bv = *(const float4*)&Bs[kk][tc << 2];
      float a_[4] = {av.x, av.y, av.z, av.w};
      float b_[4] = {bv.x, bv.y, bv.z, bv.w};
#pragma unroll
      for (int i = 0; i < 4; ++i)
#pragma unroll
        for (int j = 0; j < 4; ++j)
          acc[i][j] += a_[i] * b_[j];
    }
    __syncthreads();
  }
  float4 bsv = *(const float4*)&bias[bn + (tc << 2)];
  float bb[4] = {bsv.x, bsv.y, bsv.z, bsv.w};
#pragma unroll
  for (int i = 0; i < 4; ++i) {
    float4 o;
    o.x = acc[i][0] + bb[0];
    o.y = acc[i][1] + bb[1];
    o.z = acc[i][2] + bb[2];
    o.w = acc[i][3] + bb[3];
    *(float4*)&out[(size_t)(bm + (tr << 2) + i) * N + bn + (tc << 2)] = o;
  }
}

// ---------------------------------------------------------------- GEMM (bf16 out)
__global__ __launch_bounds__(256) void gemm_bias_bf16(const float* __restrict__ X,
                                                      const float* __restrict__ W,
                                                      const float* __restrict__ bias,
                                                      unsigned short* __restrict__ out,
                                                      int K, int N) {
  __shared__ float As[16][68];
  __shared__ float Bs[16][64];
  int tid = threadIdx.x;
  int bm = blockIdx.x * 64;
  int bn = blockIdx.y * 64;
  int tr = tid >> 4, tc = tid & 15;
  float acc[4][4] = {{0.f}};
  for (int k0 = 0; k0 < K; k0 += 16) {
#pragma unroll
    for (int i = 0; i < 4; ++i) {
      int rr = (tid >> 4) + (i << 4);
      int kk = tid & 15;
      As[kk][rr] = (k0 + kk < K) ? X[(size_t)(bm + rr) * K + (k0 + kk)] : 0.f;
    }
#pragma unroll
    for (int i = 0; i < 4; ++i) {
      int kk = (tid >> 6) + (i << 2);
      int c  = tid & 63;
      Bs[kk][c] = (k0 + kk < K) ? W[(size_t)(k0 + kk) * N + (bn + c)] : 0.f;
    }
    __syncthreads();
#pragma unroll
    for (int kk = 0; kk < 16; ++kk) {
      float4 av = *(const float4*)&As[kk][tr << 2];
      float4 bv = *(const float4*)&Bs[kk][tc << 2];
      float a_[4] = {av.x, av.y, av.z, av.w};
      float b_[4] = {bv.x, bv.y, bv.z, bv.w};
#pragma unroll
      for (int i = 0; i < 4; ++i)
#pragma unroll
        for (int j = 0; j < 4; ++j)
          acc[i][j] += a_[i] * b_[j];
    }
    __syncthreads();
  }
  float4 bsv = *(const float4*)&bias[bn + (tc << 2)];
  float bb[4] = {bsv.x, bsv.y, bsv.z, bsv.w};
#pragma unroll
  for (int i = 0; i < 4; ++i) {
    ushort4 s4;
    s4.x = f2bf(acc[i][0] + bb[0]);
    s4.y = f2bf(acc[i][1] + bb[1]);
    s4.z = f2bf(acc[i][2] + bb[2]);
    s4.w = f2bf(acc[i][3] + bb[3]);
    *(ushort4*)&out[(size_t)(bm + (tr << 2) + i) * N + bn + (tc << 2)] = s4;
  }
}

// ---------------------------------------------------------------- Attention
// 4 targets per wave, one (target, neighbor) per lane. BF16KV: k/v stored bf16.
template <int DOUT, bool BF16KV>
__global__ __launch_bounds__(256) void attn_kernel(const float* __restrict__ qp,
                                                   const void* __restrict__ kp,
                                                   const void* __restrict__ vp,
                                                   const int* __restrict__ idx,
                                                   float* __restrict__ xout) {
  constexpr int F  = DOUT / 4;    // float4 per row
  __shared__ float4 qs[4][4][F + 1];
  __shared__ int    ss[4][64];
  int lane = threadIdx.x & 63, wv = threadIdx.x >> 6;
  int t0 = blockIdx.x * 16 + wv * 4;
  int bofs = (t0 >> 12) << 12;
  int tt = lane >> 4, jj = lane & 15;
  int src = bofs + idx[(t0 + tt) * 16 + jj];
  ss[wv][lane] = src;
  const float4* qp4 = (const float4*)qp;
#pragma unroll
  for (int i = 0; i < F / 16; ++i) {
    int g = lane + 64 * i;
    qs[wv][g / F][g % F] = qp4[(size_t)t0 * F + g];
  }
  __syncthreads();

  // ---- logits
  float acc = 0.f;
  if constexpr (BF16KV) {
    const uint4* krow = (const uint4*)((const unsigned short*)kp + (size_t)src * DOUT);
#pragma unroll
    for (int cch = 0; cch < DOUT / 8; ++cch) {
      uint4 kk = krow[cch];
      float4 q0 = qs[wv][tt][2 * cch], q1 = qs[wv][tt][2 * cch + 1];
      float2 k0 = bf2(kk.x), k1 = bf2(kk.y), k2 = bf2(kk.z), k3 = bf2(kk.w);
      acc += q0.x * k0.x + q0.y * k0.y + q0.z * k1.x + q0.w * k1.y
           + q1.x * k2.x + q1.y * k2.y + q1.z * k3.x + q1.w * k3.y;
    }
  } else {
    const float4* krow = (const float4*)((const float*)kp + (size_t)src * DOUT);
#pragma unroll
    for (int f = 0; f < F; ++f) {
      float4 kk = krow[f], qq = qs[wv][tt][f];
      acc += qq.x * kk.x + qq.y * kk.y + qq.z * kk.z + qq.w * kk.w;
    }
  }
  const float scale = (DOUT == 64) ? 0.125f
                    : (DOUT == 128) ? 0.08838834764831843f : 0.0625f;
  float logit = acc * scale;
  float mx = logit;
#pragma unroll
  for (int d = 1; d <= 8; d <<= 1) mx = fmaxf(mx, __shfl_xor(mx, d));
  float e = expf(logit - mx);
  float sm = e;
#pragma unroll
  for (int d = 1; d <= 8; d <<= 1) sm += __shfl_xor(sm, d);
  float a = e / sm;

  // ---- PV
  int gbase = lane & 48;
  float4* xo4 = (float4*)xout;
  if constexpr (BF16KV) {
    constexpr int U = DOUT / 128;         // 1 (DOUT=128) or 2 (DOUT=256)
    float4 o[2 * U];
#pragma unroll
    for (int u = 0; u < 2 * U; ++u) o[u] = make_float4(0.f, 0.f, 0.f, 0.f);
#pragma unroll
    for (int j = 0; j < 16; ++j) {
      float aj = __shfl(a, gbase | j);
      const uint4* vrow =
          (const uint4*)((const unsigned short*)vp + (size_t)ss[wv][gbase | j] * DOUT);
#pragma unroll
      for (int u = 0; u < U; ++u) {
        uint4 vv = vrow[jj + 16 * u];
        float2 a0 = bf2(vv.x), a1 = bf2(vv.y), a2 = bf2(vv.z), a3 = bf2(vv.w);
        o[2 * u].x += aj * a0.x; o[2 * u].y += aj * a0.y;
        o[2 * u].z += aj * a1.x; o[2 * u].w += aj * a1.y;
        o[2 * u + 1].x += aj * a2.x; o[2 * u + 1].y += aj * a2.y;
        o[2 * u + 1].z += aj * a3.x; o[2 * u + 1].w += aj * a3.y;
      }
    }
#pragma unroll
    for (int u = 0; u < U; ++u)
#pragma unroll
      for (int h = 0; h < 2; ++h) {
        size_t oi = (size_t)(t0 + tt) * F + 2 * jj + 32 * u + h;
        float4 x4 = xo4[oi];
        float4 ov = o[2 * u + h];
        float4 r;
        r.x = fmaxf(x4.x + ov.x, 0.f);
        r.y = fmaxf(x4.y + ov.y, 0.f);
        r.z = fmaxf(x4.z + ov.z, 0.f);
        r.w = fmaxf(x4.w + ov.w, 0.f);
        xo4[oi] = r;
      }
  } else {
    constexpr int QF = DOUT / 64;
    float4 o[QF];
#pragma unroll
    for (int u = 0; u < QF; ++u) o[u] = make_float4(0.f, 0.f, 0.f, 0.f);
#pragma unroll
    for (int j = 0; j < 16; ++j) {
      float aj = __shfl(a, gbase | j);
      const float4* vrow =
          (const float4*)((const float*)vp + (size_t)ss[wv][gbase | j] * DOUT);
#pragma unroll
      for (int u = 0; u < QF; ++u) {
        float4 vv = vrow[jj + 16 * u];
        o[u].x += aj * vv.x; o[u].y += aj * vv.y;
        o[u].z += aj * vv.z; o[u].w += aj * vv.w;
      }
    }
#pragma unroll
    for (int u = 0; u < QF; ++u) {
      size_t oi = (size_t)(t0 + tt) * F + jj + 16 * u;
      float4 x4 = xo4[oi];
      float4 r;
      r.x = fmaxf(x4.x + o[u].x, 0.f);
      r.y = fmaxf(x4.y + o[u].y, 0.f);
      r.z = fmaxf(x4.z + o[u].z, 0.f);
      r.w = fmaxf(x4.w + o[u].w, 0.f);
      xo4[oi] = r;
    }
  }
}

// ---------------------------------------------------------------- Pool + head
__global__ void zero_kernel(float* g) { g[blockIdx.x * 256 + threadIdx.x] = 0.f; }

__global__ __launch_bounds__(256) void pool_kernel(const float* __restrict__ x3,
                                                   float* __restrict__ g) {
  int b = blockIdx.y, c = threadIdx.x;
  int p0 = blockIdx.x * 256;
  float m = 0.f;
  for (int p = p0; p < p0 + 256; ++p)
    m = fmaxf(m, x3[((size_t)b * NPTS + p) * 256 + c]);
  atomicMax((int*)&g[b * 256 + c], __float_as_int(m));
}

__global__ __launch_bounds__(256) void head_kernel(const float* __restrict__ g,
    const float* __restrict__ w1, const float* __restrict__ b1,
    const float* __restrict__ w2, const float* __restrict__ b2,
    const float* __restrict__ w3, const float* __restrict__ b3,
    float* __restrict__ out) {
  __shared__ float gb[256], h1[512], h2[256], lg[10];
  int b = blockIdx.x, t = threadIdx.x;
  gb[t] = g[b * 256 + t];
  __syncthreads();
#pragma unroll
  for (int half = 0; half < 2; ++half) {
    int c = t + half * 256;
    float a = b1[c];
    for (int kk = 0; kk < 256; ++kk) a += gb[kk] * w1[kk * 512 + c];
    h1[c] = fmaxf(a, 0.f);
  }
  __syncthreads();
  {
    float a = b2[t];
    for (int kk = 0; kk < 512; ++kk) a += h1[kk] * w2[kk * 256 + t];
    h2[t] = fmaxf(a, 0.f);
  }
  __syncthreads();
  if (t < 10) {
    float a = b3[t];
    for (int kk = 0; kk < 256; ++kk) a += h2[kk] * w3[kk * 10 + t];
    lg[t] = a;
  }
  __syncthreads();
  if (t < 10) {
    float mx = lg[0];
#pragma unroll
    for (int i = 1; i < 10; ++i) mx = fmaxf(mx, lg[i]);
    float s = 0.f;
#pragma unroll
    for (int i = 0; i < 10; ++i) s += expf(lg[i] - mx);
    out[b * 10 + t] = lg[t] - mx - logf(s);
  }
}

// ---------------------------------------------------------------- launch
extern "C" void kernel_launch(void* const* d_in, const int* in_sizes, int n_in,
                              void* d_out, int out_size, void* d_ws, size_t ws_size,
                              hipStream_t stream) {
  const float* pos = (const float*)d_in[0];
  const float* W[3][4]; const float* Bb[3][4];
  for (int l = 0; l < 3; ++l)
    for (int nm = 0; nm < 4; ++nm) {           // order q,k,v,s
      W[l][nm]  = (const float*)d_in[1 + l * 8 + nm * 2];
      Bb[l][nm] = (const float*)d_in[1 + l * 8 + nm * 2 + 1];
    }
  const float* fc1w = (const float*)d_in[25]; const float* fc1b = (const float*)d_in[26];
  const float* fc2w = (const float*)d_in[27]; const float* fc2b = (const float*)d_in[28];
  const float* fc3w = (const float*)d_in[29]; const float* fc3b = (const float*)d_in[30];

  int*   idxb  = (int*)d_ws;
  float* fbase = (float*)((char*)d_ws + (size_t)MTOT * NBR * 4);
  float* qb = fbase;
  float* kb = qb + (size_t)MTOT * 256;       // fp32 (L1) or bf16 (L2/3) region
  float* vb = kb + (size_t)MTOT * 256;
  float* x1 = vb + (size_t)MTOT * 256;
  float* x2 = x1 + (size_t)MTOT * 64;
  float* x3 = x2 + (size_t)MTOT * 128;
  float* g  = x3 + (size_t)MTOT * 256;
  float4* pos4 = (float4*)(g + BATCH * 256);
  unsigned short* kh = (unsigned short*)kb;
  unsigned short* vh = (unsigned short*)vb;

  prep_pos4<<<MTOT / 256, 256, 0, stream>>>(pos, pos4);
  knn_kernel<<<MTOT, 256, 0, stream>>>(pos4, idxb);

  // layer 1: din=3, dout=64 (all fp32)
  gemm_bias<<<dim3(512, 1), 256, 0, stream>>>(pos, W[0][0], Bb[0][0], qb, 3, 64);
  gemm_bias<<<dim3(512, 1), 256, 0, stream>>>(pos, W[0][1], Bb[0][1], kb, 3, 64);
  gemm_bias<<<dim3(512, 1), 256, 0, stream>>>(pos, W[0][2], Bb[0][2], vb, 3, 64);
  gemm_bias<<<dim3(512, 1), 256, 0, stream>>>(pos, W[0][3], Bb[0][3], x1, 3, 64);
  attn_kernel<64, false><<<MTOT / 16, 256, 0, stream>>>(qb, kb, vb, idxb, x1);

  // layer 2: din=64, dout=128 (k/v bf16)
  gemm_bias<<<dim3(512, 2), 256, 0, stream>>>(x1, W[1][0], Bb[1][0], qb, 64, 128);
  gemm_bias_bf16<<<dim3(512, 2), 256, 0, stream>>>(x1, W[1][1], Bb[1][1], kh, 64, 128);
  gemm_bias_bf16<<<dim3(512, 2), 256, 0, stream>>>(x1, W[1][2], Bb[1][2], vh, 64, 128);
  gemm_bias<<<dim3(512, 2), 256, 0, stream>>>(x1, W[1][3], Bb[1][3], x2, 64, 128);
  attn_kernel<128, true><<<MTOT / 16, 256, 0, stream>>>(qb, kh, vh, idxb, x2);

  // layer 3: din=128, dout=256 (k/v bf16)
  gemm_bias<<<dim3(512, 4), 256, 0, stream>>>(x2, W[2][0], Bb[2][0], qb, 128, 256);
  gemm_bias_bf16<<<dim3(512, 4), 256, 0, stream>>>(x2, W[2][1], Bb[2][1], kh, 128, 256);
  gemm_bias_bf16<<<dim3(512, 4), 256, 0, stream>>>(x2, W[2][2], Bb[2][2], vh, 128, 256);
  gemm_bias<<<dim3(512, 4), 256, 0, stream>>>(x2, W[2][3], Bb[2][3], x3, 128, 256);
  attn_kernel<256, true><<<MTOT / 16, 256, 0, stream>>>(qb, kh, vh, idxb, x3);

  // global max pool + MLP head
  zero_kernel<<<8, 256, 0, stream>>>(g);
  pool_kernel<<<dim3(16, 8), 256, 0, stream>>>(x3, g);
  head_kernel<<<8, 256, 0, stream>>>(g, fc1w, fc1b, fc2w, fc2b, fc3w, fc3b,
                                     (float*)d_out);
}

// Round 5
// 575.543 us; speedup vs baseline: 3.3285x; 1.0920x over previous
//
#include <hip/hip_runtime.h>
#include <math.h>

#define BATCH 8
#define NPTS  4096
#define NBR   16
#define MTOT  (BATCH * NPTS)   // 32768

#define KNN_BINS 4096
#define KNN_PAD  (KNN_BINS + KNN_BINS / 32)   // pad word every 32 bins
#define HADDR(b) ((b) + ((b) >> 5))
#define KNN_CAP  64

typedef unsigned short ushort_t;
typedef __attribute__((ext_vector_type(8))) short bf16x8;
typedef __attribute__((ext_vector_type(4))) float f32x4;

__device__ inline unsigned short f2bf(float f) {   // RNE bf16 bits
  unsigned u = __float_as_uint(f);
  return (unsigned short)((u + 0x7FFFu + ((u >> 16) & 1u)) >> 16);
}
__device__ inline float bff(unsigned short h) {
  return __uint_as_float(((unsigned)h) << 16);
}
__device__ inline float2 bf2(unsigned u) {         // two packed bf16 -> floats
  return make_float2(__uint_as_float(u << 16), __uint_as_float(u & 0xFFFF0000u));
}

// ---------------------------------------------------------------- prep
__global__ __launch_bounds__(256) void prep_pos4(const float* __restrict__ pos,
                                                 float4* __restrict__ pos4) {
  int i = blockIdx.x * 256 + threadIdx.x;
  float x = pos[i * 3 + 0], y = pos[i * 3 + 1], z = pos[i * 3 + 2];
  pos4[i] = make_float4(x, y, z, x * x + y * y + z * z);
}

// ---------------------------------------------------------------- KNN
// One block = one target. Histogram select, PADDED layout hist[b + b/32]:
// atomics spread by mantissa low bits; sweep addr = 16*tid + tid/2 + i covers
// all 32 banks across a wave (2-way only). Prefix via wave shfl scan.
__global__ __launch_bounds__(256) void knn_kernel(const float4* __restrict__ pos4,
                                                  int* __restrict__ idxout) {
  __shared__ unsigned hist[KNN_PAD];
  __shared__ unsigned wsum[4];
  __shared__ unsigned long long cand[KNN_CAP];
  __shared__ unsigned nPiv, nOut, s_pivot, s_c0;

  int t = blockIdx.x;
  int b = t >> 12;
  int p = t & (NPTS - 1);
  const float4* base = pos4 + ((size_t)b << 12);
  float4 me = base[p];

  int tid = threadIdx.x;
  int lane = tid & 63, wv = tid >> 6;
  for (int i = tid; i < KNN_PAD; i += 256) hist[i] = 0;
  if (tid == 0) { nPiv = 0; nOut = 0; }
  __syncthreads();

  unsigned key[16];
#pragma unroll
  for (int j = 0; j < 16; ++j) {
    int q = tid + j * 256;
    float4 o = base[q];
    float d2 = me.w + o.w - 2.f * (me.x * o.x + me.y * o.y + me.z * o.z);
    unsigned u = __float_as_uint(d2);
    unsigned k2 = u ^ (unsigned)(((int)u >> 31) | 0x80000000);
    key[j] = (q == p) ? 0xFFFFFFFFu : k2;
    atomicAdd(&hist[HADDR(key[j] >> 20)], 1u);
  }
  __syncthreads();

  // per-thread count of its 16 contiguous bins [tid*16, tid*16+16)
  unsigned s = 0;
#pragma unroll
  for (int i = 0; i < 16; ++i) s += hist[HADDR(tid * 16 + i)];
  unsigned c = s;
#pragma unroll
  for (int d = 1; d < 64; d <<= 1) {
    unsigned x = __shfl_up(c, d);
    if (lane >= d) c += x;
  }
  if (lane == 63) wsum[wv] = c;
  __syncthreads();
  unsigned off = 0;
#pragma unroll
  for (int w = 0; w < 4; ++w) off += (w < wv) ? wsum[w] : 0u;
  unsigned cum_incl = c + off;
  unsigned cum_excl = cum_incl - s;

  if (cum_excl < NBR && cum_incl >= NBR) {   // unique owner thread
    unsigned h[16];
#pragma unroll
    for (int i = 0; i < 16; ++i) h[i] = hist[HADDR(tid * 16 + i)];
    unsigned c0 = cum_excl; int bin = tid * 16; bool done = false;
#pragma unroll
    for (int i = 0; i < 16; ++i) {
      if (!done) {
        if (c0 + h[i] >= NBR) done = true;
        else { c0 += h[i]; ++bin; }
      }
    }
    s_pivot = (unsigned)bin; s_c0 = c0;
  }
  __syncthreads();

  unsigned pivot = s_pivot, c0 = s_c0;
  int* op = idxout + (size_t)t * NBR;
#pragma unroll
  for (int j = 0; j < 16; ++j) {
    unsigned bin = key[j] >> 20;
    if (bin < pivot) {
      unsigned slot = atomicAdd(&nOut, 1u);
      op[slot] = tid + j * 256;
    } else if (bin == pivot) {
      unsigned slot = atomicAdd(&nPiv, 1u);
      if (slot < KNN_CAP)
        cand[slot] = ((unsigned long long)key[j] << 32) | (unsigned)(tid + j * 256);
    }
  }
  __syncthreads();

  if (tid < 64) {
    int n = (int)(nPiv < KNN_CAP ? nPiv : KNN_CAP);
    int need = NBR - (int)c0;
    unsigned long long val = (tid < n) ? cand[tid] : ~0ULL;
    for (int it = 0; it < need; ++it) {
      unsigned long long m = val;
#pragma unroll
      for (int d = 1; d < 64; d <<= 1) {
        unsigned long long o = __shfl_xor(m, d);
        m = (o < m) ? o : m;
      }
      if (val == m) {
        op[c0 + it] = (int)(m & 0xFFFFFFFFu);
        val = ~0ULL;
      }
    }
  }
}

// ---------------------------------------------------------------- split fp32 -> bf16 hi/lo
__global__ __launch_bounds__(256) void split_bf16(const float* __restrict__ in,
                                                  ushort_t* __restrict__ hi,
                                                  ushort_t* __restrict__ lo, int n4) {
  int i = blockIdx.x * 256 + threadIdx.x;
  if (i >= n4) return;
  float4 v = ((const float4*)in)[i];
  ushort4 h, l;
  h.x = f2bf(v.x); l.x = f2bf(v.x - bff(h.x));
  h.y = f2bf(v.y); l.y = f2bf(v.y - bff(h.y));
  h.z = f2bf(v.z); l.z = f2bf(v.z - bff(h.z));
  h.w = f2bf(v.w); l.w = f2bf(v.w - bff(h.w));
  ((ushort4*)hi)[i] = h;
  ((ushort4*)lo)[i] = l;
}

// weight: W[K][N] fp32 -> transposed Wt[N][K] bf16 hi/lo
__global__ __launch_bounds__(256) void split_wt(const float* __restrict__ w,
                                                ushort_t* __restrict__ th,
                                                ushort_t* __restrict__ tl,
                                                int K, int N) {
  int i = blockIdx.x * 256 + threadIdx.x;
  if (i >= K * N) return;
  int k = i / N, n = i - k * N;
  float v = w[i];
  unsigned short h = f2bf(v);
  th[(size_t)n * K + k] = h;
  tl[(size_t)n * K + k] = f2bf(v - bff(h));
}

// ---------------------------------------------------------------- MFMA GEMM (split bf16)
// C[M,N] = X[M,K]@W[K,N] + bias, X as hi/lo bf16 [M][K], W as hi/lo bf16 [N][K].
// 256 thr = 2x2 waves, wave does 32x32 via 2x2 mfma_f32_16x16x32_bf16.
// A: row=lane&15, k=(lane>>4)*8+j ; B: col=lane&15, k=(lane>>4)*8+j ;
// C/D: col=lane&15, row=(lane>>4)*4+reg  (guide-verified m89).
template <bool OUTBF16>
__global__ __launch_bounds__(256) void gemm_mfma(const ushort_t* __restrict__ Xh,
                                                 const ushort_t* __restrict__ Xl,
                                                 const ushort_t* __restrict__ Wh,
                                                 const ushort_t* __restrict__ Wl,
                                                 const float* __restrict__ bias,
                                                 void* __restrict__ out,
                                                 int K, int N) {
  int lane = threadIdx.x & 63, wv = threadIdx.x >> 6;
  int bm = blockIdx.x * 64 + (wv >> 1) * 32;
  int bn = blockIdx.y * 64 + (wv & 1) * 32;
  int r = lane & 15, g4 = lane >> 4;
  f32x4 acc[2][2];
#pragma unroll
  for (int i = 0; i < 2; ++i)
#pragma unroll
    for (int j = 0; j < 2; ++j) acc[i][j] = (f32x4){0.f, 0.f, 0.f, 0.f};

  for (int k0 = 0; k0 < K; k0 += 32) {
    int kb = k0 + g4 * 8;
    bf16x8 ah[2], al[2], bh[2], bl[2];
#pragma unroll
    for (int i = 0; i < 2; ++i) {
      size_t xo = (size_t)(bm + i * 16 + r) * K + kb;
      ah[i] = *(const bf16x8*)(Xh + xo);
      al[i] = *(const bf16x8*)(Xl + xo);
      size_t wo = (size_t)(bn + i * 16 + r) * K + kb;
      bh[i] = *(const bf16x8*)(Wh + wo);
      bl[i] = *(const bf16x8*)(Wl + wo);
    }
#pragma unroll
    for (int i = 0; i < 2; ++i)
#pragma unroll
      for (int j = 0; j < 2; ++j) {
        acc[i][j] = __builtin_amdgcn_mfma_f32_16x16x32_bf16(ah[i], bh[j], acc[i][j], 0, 0, 0);
        acc[i][j] = __builtin_amdgcn_mfma_f32_16x16x32_bf16(ah[i], bl[j], acc[i][j], 0, 0, 0);
        acc[i][j] = __builtin_amdgcn_mfma_f32_16x16x32_bf16(al[i], bh[j], acc[i][j], 0, 0, 0);
      }
  }
#pragma unroll
  for (int i = 0; i < 2; ++i)
#pragma unroll
    for (int j = 0; j < 2; ++j) {
      int col = bn + j * 16 + r;
      float bv = bias[col];
#pragma unroll
      for (int tr = 0; tr < 4; ++tr) {
        int row = bm + i * 16 + g4 * 4 + tr;
        float val = acc[i][j][tr] + bv;
        if constexpr (OUTBF16)
          ((ushort_t*)out)[(size_t)row * N + col] = f2bf(val);
        else
          ((float*)out)[(size_t)row * N + col] = val;
      }
    }
}

// ---------------------------------------------------------------- GEMM (fp32, layer-1 K=3)
__global__ __launch_bounds__(256) void gemm_bias(const float* __restrict__ X,
                                                 const float* __restrict__ W,
                                                 const float* __restrict__ bias,
                                                 float* __restrict__ out,
                                                 int K, int N) {
  __shared__ float As[16][68];
  __shared__ float Bs[16][64];
  int tid = threadIdx.x;
  int bm = blockIdx.x * 64;
  int bn = blockIdx.y * 64;
  int tr = tid >> 4, tc = tid & 15;
  float acc[4][4] = {{0.f}};
  for (int k0 = 0; k0 < K; k0 += 16) {
#pragma unroll
    for (int i = 0; i < 4; ++i) {
      int rr = (tid >> 4) + (i << 4);
      int kk = tid & 15;
      As[kk][rr] = (k0 + kk < K) ? X[(size_t)(bm + rr) * K + (k0 + kk)] : 0.f;
    }
#pragma unroll
    for (int i = 0; i < 4; ++i) {
      int kk = (tid >> 6) + (i << 2);
      int c  = tid & 63;
      Bs[kk][c] = (k0 + kk < K) ? W[(size_t)(k0 + kk) * N + (bn + c)] : 0.f;
    }
    __syncthreads();
#pragma unroll
    for (int kk = 0; kk < 16; ++kk) {
      float4 av = *(const float4*)&As[kk][tr << 2];
      float4 bv = *(const float4*)&Bs[kk][tc << 2];
      float a_[4] = {av.x, av.y, av.z, av.w};
      float b_[4] = {bv.x, bv.y, bv.z, bv.w};
#pragma unroll
      for (int i = 0; i < 4; ++i)
#pragma unroll
        for (int j = 0; j < 4; ++j)
          acc[i][j] += a_[i] * b_[j];
    }
    __syncthreads();
  }
  float4 bsv = *(const float4*)&bias[bn + (tc << 2)];
  float bb[4] = {bsv.x, bsv.y, bsv.z, bsv.w};
#pragma unroll
  for (int i = 0; i < 4; ++i) {
    float4 o;
    o.x = acc[i][0] + bb[0];
    o.y = acc[i][1] + bb[1];
    o.z = acc[i][2] + bb[2];
    o.w = acc[i][3] + bb[3];
    *(float4*)&out[(size_t)(bm + (tr << 2) + i) * N + bn + (tc << 2)] = o;
  }
}

// ---------------------------------------------------------------- Attention
template <int DOUT, bool BF16KV>
__global__ __launch_bounds__(256) void attn_kernel(const float* __restrict__ qp,
                                                   const void* __restrict__ kp,
                                                   const void* __restrict__ vp,
                                                   const int* __restrict__ idx,
                                                   float* __restrict__ xout) {
  constexpr int F  = DOUT / 4;
  __shared__ float4 qs[4][4][F + 1];
  __shared__ int    ss[4][64];
  int lane = threadIdx.x & 63, wv = threadIdx.x >> 6;
  int t0 = blockIdx.x * 16 + wv * 4;
  int bofs = (t0 >> 12) << 12;
  int tt = lane >> 4, jj = lane & 15;
  int src = bofs + idx[(t0 + tt) * 16 + jj];
  ss[wv][lane] = src;
  const float4* qp4 = (const float4*)qp;
#pragma unroll
  for (int i = 0; i < F / 16; ++i) {
    int g = lane + 64 * i;
    qs[wv][g / F][g % F] = qp4[(size_t)t0 * F + g];
  }
  __syncthreads();

  float acc = 0.f;
  if constexpr (BF16KV) {
    const uint4* krow = (const uint4*)((const ushort_t*)kp + (size_t)src * DOUT);
#pragma unroll
    for (int cch = 0; cch < DOUT / 8; ++cch) {
      uint4 kk = krow[cch];
      float4 q0 = qs[wv][tt][2 * cch], q1 = qs[wv][tt][2 * cch + 1];
      float2 k0 = bf2(kk.x), k1 = bf2(kk.y), k2 = bf2(kk.z), k3 = bf2(kk.w);
      acc += q0.x * k0.x + q0.y * k0.y + q0.z * k1.x + q0.w * k1.y
           + q1.x * k2.x + q1.y * k2.y + q1.z * k3.x + q1.w * k3.y;
    }
  } else {
    const float4* krow = (const float4*)((const float*)kp + (size_t)src * DOUT);
#pragma unroll
    for (int f = 0; f < F; ++f) {
      float4 kk = krow[f], qq = qs[wv][tt][f];
      acc += qq.x * kk.x + qq.y * kk.y + qq.z * kk.z + qq.w * kk.w;
    }
  }
  const float scale = (DOUT == 64) ? 0.125f
                    : (DOUT == 128) ? 0.08838834764831843f : 0.0625f;
  float logit = acc * scale;
  float mx = logit;
#pragma unroll
  for (int d = 1; d <= 8; d <<= 1) mx = fmaxf(mx, __shfl_xor(mx, d));
  float e = expf(logit - mx);
  float sm = e;
#pragma unroll
  for (int d = 1; d <= 8; d <<= 1) sm += __shfl_xor(sm, d);
  float a = e / sm;

  int gbase = lane & 48;
  float4* xo4 = (float4*)xout;
  if constexpr (BF16KV) {
    constexpr int U = DOUT / 128;
    float4 o[2 * U];
#pragma unroll
    for (int u = 0; u < 2 * U; ++u) o[u] = make_float4(0.f, 0.f, 0.f, 0.f);
#pragma unroll
    for (int j = 0; j < 16; ++j) {
      float aj = __shfl(a, gbase | j);
      const uint4* vrow =
          (const uint4*)((const ushort_t*)vp + (size_t)ss[wv][gbase | j] * DOUT);
#pragma unroll
      for (int u = 0; u < U; ++u) {
        uint4 vv = vrow[jj + 16 * u];
        float2 a0 = bf2(vv.x), a1 = bf2(vv.y), a2 = bf2(vv.z), a3 = bf2(vv.w);
        o[2 * u].x += aj * a0.x; o[2 * u].y += aj * a0.y;
        o[2 * u].z += aj * a1.x; o[2 * u].w += aj * a1.y;
        o[2 * u + 1].x += aj * a2.x; o[2 * u + 1].y += aj * a2.y;
        o[2 * u + 1].z += aj * a3.x; o[2 * u + 1].w += aj * a3.y;
      }
    }
#pragma unroll
    for (int u = 0; u < U; ++u)
#pragma unroll
      for (int h = 0; h < 2; ++h) {
        size_t oi = (size_t)(t0 + tt) * F + 2 * jj + 32 * u + h;
        float4 x4 = xo4[oi];
        float4 ov = o[2 * u + h];
        float4 rr;
        rr.x = fmaxf(x4.x + ov.x, 0.f);
        rr.y = fmaxf(x4.y + ov.y, 0.f);
        rr.z = fmaxf(x4.z + ov.z, 0.f);
        rr.w = fmaxf(x4.w + ov.w, 0.f);
        xo4[oi] = rr;
      }
  } else {
    constexpr int QF = DOUT / 64;
    float4 o[QF];
#pragma unroll
    for (int u = 0; u < QF; ++u) o[u] = make_float4(0.f, 0.f, 0.f, 0.f);
#pragma unroll
    for (int j = 0; j < 16; ++j) {
      float aj = __shfl(a, gbase | j);
      const float4* vrow =
          (const float4*)((const float*)vp + (size_t)ss[wv][gbase | j] * DOUT);
#pragma unroll
      for (int u = 0; u < QF; ++u) {
        float4 vv = vrow[jj + 16 * u];
        o[u].x += aj * vv.x; o[u].y += aj * vv.y;
        o[u].z += aj * vv.z; o[u].w += aj * vv.w;
      }
    }
#pragma unroll
    for (int u = 0; u < QF; ++u) {
      size_t oi = (size_t)(t0 + tt) * F + jj + 16 * u;
      float4 x4 = xo4[oi];
      float4 rr;
      rr.x = fmaxf(x4.x + o[u].x, 0.f);
      rr.y = fmaxf(x4.y + o[u].y, 0.f);
      rr.z = fmaxf(x4.z + o[u].z, 0.f);
      rr.w = fmaxf(x4.w + o[u].w, 0.f);
      xo4[oi] = rr;
    }
  }
}

// ---------------------------------------------------------------- Pool + head
__global__ void zero_kernel(float* g) { g[blockIdx.x * 256 + threadIdx.x] = 0.f; }

__global__ __launch_bounds__(256) void pool_kernel(const float* __restrict__ x3,
                                                   float* __restrict__ g) {
  int b = blockIdx.y, c = threadIdx.x;
  int p0 = blockIdx.x * 256;
  float m = 0.f;
  for (int p = p0; p < p0 + 256; ++p)
    m = fmaxf(m, x3[((size_t)b * NPTS + p) * 256 + c]);
  atomicMax((int*)&g[b * 256 + c], __float_as_int(m));
}

__global__ __launch_bounds__(256) void head_kernel(const float* __restrict__ g,
    const float* __restrict__ w1, const float* __restrict__ b1,
    const float* __restrict__ w2, const float* __restrict__ b2,
    const float* __restrict__ w3, const float* __restrict__ b3,
    float* __restrict__ out) {
  __shared__ float gb[256], h1[512], h2[256], lg[10];
  int b = blockIdx.x, t = threadIdx.x;
  gb[t] = g[b * 256 + t];
  __syncthreads();
#pragma unroll
  for (int half = 0; half < 2; ++half) {
    int c = t + half * 256;
    float a = b1[c];
    for (int kk = 0; kk < 256; ++kk) a += gb[kk] * w1[kk * 512 + c];
    h1[c] = fmaxf(a, 0.f);
  }
  __syncthreads();
  {
    float a = b2[t];
    for (int kk = 0; kk < 512; ++kk) a += h1[kk] * w2[kk * 256 + t];
    h2[t] = fmaxf(a, 0.f);
  }
  __syncthreads();
  if (t < 10) {
    float a = b3[t];
    for (int kk = 0; kk < 256; ++kk) a += h2[kk] * w3[kk * 10 + t];
    lg[t] = a;
  }
  __syncthreads();
  if (t < 10) {
    float mx = lg[0];
#pragma unroll
    for (int i = 1; i < 10; ++i) mx = fmaxf(mx, lg[i]);
    float s = 0.f;
#pragma unroll
    for (int i = 0; i < 10; ++i) s += expf(lg[i] - mx);
    out[b * 10 + t] = lg[t] - mx - logf(s);
  }
}

// ---------------------------------------------------------------- launch
extern "C" void kernel_launch(void* const* d_in, const int* in_sizes, int n_in,
                              void* d_out, int out_size, void* d_ws, size_t ws_size,
                              hipStream_t stream) {
  const float* pos = (const float*)d_in[0];
  const float* W[3][4]; const float* Bb[3][4];
  for (int l = 0; l < 3; ++l)
    for (int nm = 0; nm < 4; ++nm) {           // order q,k,v,s
      W[l][nm]  = (const float*)d_in[1 + l * 8 + nm * 2];
      Bb[l][nm] = (const float*)d_in[1 + l * 8 + nm * 2 + 1];
    }
  const float* fc1w = (const float*)d_in[25]; const float* fc1b = (const float*)d_in[26];
  const float* fc2w = (const float*)d_in[27]; const float* fc2b = (const float*)d_in[28];
  const float* fc3w = (const float*)d_in[29]; const float* fc3b = (const float*)d_in[30];

  int*   idxb  = (int*)d_ws;
  float* fbase = (float*)((char*)d_ws + (size_t)MTOT * NBR * 4);
  float* qb = fbase;
  float* kb = qb + (size_t)MTOT * 256;
  float* vb = kb + (size_t)MTOT * 256;
  float* x1 = vb + (size_t)MTOT * 256;
  float* x2 = x1 + (size_t)MTOT * 64;
  float* x3 = x2 + (size_t)MTOT * 128;
  float* g  = x3 + (size_t)MTOT * 256;
  float4* pos4 = (float4*)(g + BATCH * 256);
  ushort_t* xsh = (ushort_t*)(pos4 + MTOT);
  ushort_t* xsl = xsh + (size_t)MTOT * 128;
  ushort_t* wsp = xsl + (size_t)MTOT * 128;   // 8 buffers of 32768 ushorts
  unsigned short* kh = (unsigned short*)kb;
  unsigned short* vh = (unsigned short*)vb;

  prep_pos4<<<MTOT / 256, 256, 0, stream>>>(pos, pos4);
  knn_kernel<<<MTOT, 256, 0, stream>>>(pos4, idxb);

  // layer 1: din=3, dout=64 (fp32 vector GEMM; K=3 too small for MFMA)
  gemm_bias<<<dim3(512, 1), 256, 0, stream>>>(pos, W[0][0], Bb[0][0], qb, 3, 64);
  gemm_bias<<<dim3(512, 1), 256, 0, stream>>>(pos, W[0][1], Bb[0][1], kb, 3, 64);
  gemm_bias<<<dim3(512, 1), 256, 0, stream>>>(pos, W[0][2], Bb[0][2], vb, 3, 64);
  gemm_bias<<<dim3(512, 1), 256, 0, stream>>>(pos, W[0][3], Bb[0][3], x1, 3, 64);
  attn_kernel<64, false><<<MTOT / 16, 256, 0, stream>>>(qb, kb, vb, idxb, x1);

  // layer 2: din=64, dout=128 — split-bf16 MFMA GEMMs
  split_bf16<<<(MTOT * 64 / 4) / 256, 256, 0, stream>>>(x1, xsh, xsl, MTOT * 64 / 4);
  {
    void* outs[4] = {qb, kh, vh, x2};
    for (int nm = 0; nm < 4; ++nm) {
      ushort_t* th = wsp + nm * 2 * 32768;
      ushort_t* tl = th + 32768;
      split_wt<<<(64 * 128 + 255) / 256, 256, 0, stream>>>(W[1][nm], th, tl, 64, 128);
      if (nm == 1 || nm == 2)
        gemm_mfma<true><<<dim3(512, 2), 256, 0, stream>>>(xsh, xsl, th, tl, Bb[1][nm], outs[nm], 64, 128);
      else
        gemm_mfma<false><<<dim3(512, 2), 256, 0, stream>>>(xsh, xsl, th, tl, Bb[1][nm], outs[nm], 64, 128);
    }
  }
  attn_kernel<128, true><<<MTOT / 16, 256, 0, stream>>>(qb, kh, vh, idxb, x2);

  // layer 3: din=128, dout=256 — split-bf16 MFMA GEMMs
  split_bf16<<<(MTOT * 128 / 4) / 256, 256, 0, stream>>>(x2, xsh, xsl, MTOT * 128 / 4);
  {
    void* outs[4] = {qb, kh, vh, x3};
    for (int nm = 0; nm < 4; ++nm) {
      ushort_t* th = wsp + nm * 2 * 32768;
      ushort_t* tl = th + 32768;
      split_wt<<<(128 * 256 + 255) / 256, 256, 0, stream>>>(W[2][nm], th, tl, 128, 256);
      if (nm == 1 || nm == 2)
        gemm_mfma<true><<<dim3(512, 4), 256, 0, stream>>>(xsh, xsl, th, tl, Bb[2][nm], outs[nm], 128, 256);
      else
        gemm_mfma<false><<<dim3(512, 4), 256, 0, stream>>>(xsh, xsl, th, tl, Bb[2][nm], outs[nm], 128, 256);
    }
  }
  attn_kernel<256, true><<<MTOT / 16, 256, 0, stream>>>(qb, kh, vh, idxb, x3);

  // global max pool + MLP head
  zero_kernel<<<8, 256, 0, stream>>>(g);
  pool_kernel<<<dim3(16, 8), 256, 0, stream>>>(x3, g);
  head_kernel<<<8, 256, 0, stream>>>(g, fc1w, fc1b, fc2w, fc2b, fc3w, fc3b,
                                     (float*)d_out);
}

// Round 6
// 555.668 us; speedup vs baseline: 3.4476x; 1.0358x over previous
//
#include <hip/hip_runtime.h>
#include <math.h>

#define BATCH 8
#define NPTS  4096
#define NBR   16
#define MTOT  (BATCH * NPTS)   // 32768

#define KNN_BINS  2048                        // top-11 bits of flipped float
#define KNN_SHIFT 21
#define KNN_PAD   (KNN_BINS + KNN_BINS / 32)  // pad word every 32 bins -> 2112
#define HADDR(b)  ((b) + ((b) >> 5))
#define KNN_CAP   128

typedef unsigned short ushort_t;
typedef __attribute__((ext_vector_type(8))) short bf16x8;
typedef __attribute__((ext_vector_type(4))) float f32x4;

__device__ inline unsigned short f2bf(float f) {   // RNE bf16 bits
  unsigned u = __float_as_uint(f);
  return (unsigned short)((u + 0x7FFFu + ((u >> 16) & 1u)) >> 16);
}
__device__ inline float bff(unsigned short h) {
  return __uint_as_float(((unsigned)h) << 16);
}
__device__ inline float2 bf2(unsigned u) {         // two packed bf16 -> floats
  return make_float2(__uint_as_float(u << 16), __uint_as_float(u & 0xFFFF0000u));
}

// ---------------------------------------------------------------- prep
__global__ __launch_bounds__(256) void prep_pos4(const float* __restrict__ pos,
                                                 float4* __restrict__ pos4) {
  int i = blockIdx.x * 256 + threadIdx.x;
  float x = pos[i * 3 + 0], y = pos[i * 3 + 1], z = pos[i * 3 + 2];
  pos4[i] = make_float4(x, y, z, x * x + y * y + z * z);
}

// ---------------------------------------------------------------- KNN
// One block = one target. 2048-bin padded histogram select.
__global__ __launch_bounds__(256) void knn_kernel(const float4* __restrict__ pos4,
                                                  int* __restrict__ idxout) {
  __shared__ unsigned hist[KNN_PAD];
  __shared__ unsigned wsum[4];
  __shared__ unsigned long long cand[KNN_CAP];
  __shared__ unsigned nPiv, nOut, s_pivot, s_c0;

  int t = blockIdx.x;
  int b = t >> 12;
  int p = t & (NPTS - 1);
  const float4* base = pos4 + ((size_t)b << 12);
  float4 me = base[p];

  int tid = threadIdx.x;
  int lane = tid & 63, wv = tid >> 6;
#pragma unroll
  for (int i = 0; i < 5; ++i) {                 // zero 2112 words as uint2
    int w = tid + i * 256;
    if (w < KNN_PAD / 2) ((uint2*)hist)[w] = make_uint2(0u, 0u);
  }
  if (tid == 0) { nPiv = 0; nOut = 0; }
  __syncthreads();

  unsigned key[16];
#pragma unroll
  for (int j = 0; j < 16; ++j) {
    int q = tid + j * 256;
    float4 o = base[q];
    float d2 = me.w + o.w - 2.f * (me.x * o.x + me.y * o.y + me.z * o.z);
    unsigned u = __float_as_uint(d2);
    unsigned k2 = u ^ (unsigned)(((int)u >> 31) | 0x80000000);
    key[j] = (q == p) ? 0xFFFFFFFFu : k2;
    atomicAdd(&hist[HADDR(key[j] >> KNN_SHIFT)], 1u);
  }
  __syncthreads();

  // per-thread count of its 8 contiguous bins [tid*8, tid*8+8)
  unsigned s = 0;
#pragma unroll
  for (int i = 0; i < 8; ++i) s += hist[HADDR(tid * 8 + i)];
  unsigned c = s;
#pragma unroll
  for (int d = 1; d < 64; d <<= 1) {
    unsigned x = __shfl_up(c, d);
    if (lane >= d) c += x;
  }
  if (lane == 63) wsum[wv] = c;
  __syncthreads();
  unsigned off = 0;
#pragma unroll
  for (int w = 0; w < 4; ++w) off += (w < wv) ? wsum[w] : 0u;
  unsigned cum_incl = c + off;
  unsigned cum_excl = cum_incl - s;

  if (cum_excl < NBR && cum_incl >= NBR) {   // unique owner thread
    unsigned h[8];
#pragma unroll
    for (int i = 0; i < 8; ++i) h[i] = hist[HADDR(tid * 8 + i)];
    unsigned c0 = cum_excl; int bin = tid * 8; bool done = false;
#pragma unroll
    for (int i = 0; i < 8; ++i) {
      if (!done) {
        if (c0 + h[i] >= NBR) done = true;
        else { c0 += h[i]; ++bin; }
      }
    }
    s_pivot = (unsigned)bin; s_c0 = c0;
  }
  __syncthreads();

  unsigned pivot = s_pivot, c0 = s_c0;
  int* op = idxout + (size_t)t * NBR;
#pragma unroll
  for (int j = 0; j < 16; ++j) {
    unsigned bin = key[j] >> KNN_SHIFT;
    if (bin < pivot) {
      unsigned slot = atomicAdd(&nOut, 1u);
      op[slot] = tid + j * 256;
    } else if (bin == pivot) {
      unsigned slot = atomicAdd(&nPiv, 1u);
      if (slot < KNN_CAP)
        cand[slot] = ((unsigned long long)key[j] << 32) | (unsigned)(tid + j * 256);
    }
  }
  __syncthreads();

  if (tid < 64) {
    int n = (int)(nPiv < KNN_CAP ? nPiv : KNN_CAP);
    int need = NBR - (int)c0;
    unsigned long long v0 = (tid < n) ? cand[tid] : ~0ULL;
    unsigned long long v1 = (tid + 64 < n) ? cand[tid + 64] : ~0ULL;
    for (int it = 0; it < need; ++it) {
      unsigned long long val = (v0 < v1) ? v0 : v1;
      unsigned long long m = val;
#pragma unroll
      for (int d = 1; d < 64; d <<= 1) {
        unsigned long long o = __shfl_xor(m, d);
        m = (o < m) ? o : m;
      }
      if (val == m && val != ~0ULL) {       // unique winner (idx in key)
        if (v0 == m) v0 = ~0ULL; else v1 = ~0ULL;
        op[c0 + it] = (int)(m & 0xFFFFFFFFu);
      }
    }
  }
}

// ---------------------------------------------------------------- weight split
// W[K][N] fp32 -> transposed Wt[N][K] bf16 hi/lo
__global__ __launch_bounds__(256) void split_wt(const float* __restrict__ w,
                                                ushort_t* __restrict__ th,
                                                ushort_t* __restrict__ tl,
                                                int K, int N) {
  int i = blockIdx.x * 256 + threadIdx.x;
  if (i >= K * N) return;
  int k = i / N, n = i - k * N;
  float v = w[i];
  unsigned short h = f2bf(v);
  th[(size_t)n * K + k] = h;
  tl[(size_t)n * K + k] = f2bf(v - bff(h));
}

// ---------------------------------------------------------------- MFMA GEMM (split bf16)
// C[M,N] = X[M,K]@W[K,N] + bias, X hi/lo bf16 [M][K], W hi/lo bf16 [N][K].
// 256 thr = 2x2 waves, wave does 32x32 via 2x2 mfma_f32_16x16x32_bf16.
template <bool OUTBF16>
__global__ __launch_bounds__(256) void gemm_mfma(const ushort_t* __restrict__ Xh,
                                                 const ushort_t* __restrict__ Xl,
                                                 const ushort_t* __restrict__ Wh,
                                                 const ushort_t* __restrict__ Wl,
                                                 const float* __restrict__ bias,
                                                 void* __restrict__ out,
                                                 int K, int N) {
  int lane = threadIdx.x & 63, wv = threadIdx.x >> 6;
  int bm = blockIdx.x * 64 + (wv >> 1) * 32;
  int bn = blockIdx.y * 64 + (wv & 1) * 32;
  int r = lane & 15, g4 = lane >> 4;
  f32x4 acc[2][2];
#pragma unroll
  for (int i = 0; i < 2; ++i)
#pragma unroll
    for (int j = 0; j < 2; ++j) acc[i][j] = (f32x4){0.f, 0.f, 0.f, 0.f};

  for (int k0 = 0; k0 < K; k0 += 32) {
    int kb = k0 + g4 * 8;
    bf16x8 ah[2], al[2], bh[2], bl[2];
#pragma unroll
    for (int i = 0; i < 2; ++i) {
      size_t xo = (size_t)(bm + i * 16 + r) * K + kb;
      ah[i] = *(const bf16x8*)(Xh + xo);
      al[i] = *(const bf16x8*)(Xl + xo);
      size_t wo = (size_t)(bn + i * 16 + r) * K + kb;
      bh[i] = *(const bf16x8*)(Wh + wo);
      bl[i] = *(const bf16x8*)(Wl + wo);
    }
#pragma unroll
    for (int i = 0; i < 2; ++i)
#pragma unroll
      for (int j = 0; j < 2; ++j) {
        acc[i][j] = __builtin_amdgcn_mfma_f32_16x16x32_bf16(ah[i], bh[j], acc[i][j], 0, 0, 0);
        acc[i][j] = __builtin_amdgcn_mfma_f32_16x16x32_bf16(ah[i], bl[j], acc[i][j], 0, 0, 0);
        acc[i][j] = __builtin_amdgcn_mfma_f32_16x16x32_bf16(al[i], bh[j], acc[i][j], 0, 0, 0);
      }
  }
#pragma unroll
  for (int i = 0; i < 2; ++i)
#pragma unroll
    for (int j = 0; j < 2; ++j) {
      int col = bn + j * 16 + r;
      float bv = bias[col];
#pragma unroll
      for (int tr = 0; tr < 4; ++tr) {
        int row = bm + i * 16 + g4 * 4 + tr;
        float val = acc[i][j][tr] + bv;
        if constexpr (OUTBF16)
          ((ushort_t*)out)[(size_t)row * N + col] = f2bf(val);
        else
          ((float*)out)[(size_t)row * N + col] = val;
      }
    }
}

// ---------------------------------------------------------------- GEMM (vector, layer-1 K=3)
template <bool OUTBF16>
__global__ __launch_bounds__(256) void gemm_bias(const float* __restrict__ X,
                                                 const float* __restrict__ W,
                                                 const float* __restrict__ bias,
                                                 void* __restrict__ out,
                                                 int K, int N) {
  __shared__ float As[16][68];
  __shared__ float Bs[16][64];
  int tid = threadIdx.x;
  int bm = blockIdx.x * 64;
  int bn = blockIdx.y * 64;
  int tr = tid >> 4, tc = tid & 15;
  float acc[4][4] = {{0.f}};
  for (int k0 = 0; k0 < K; k0 += 16) {
#pragma unroll
    for (int i = 0; i < 4; ++i) {
      int rr = (tid >> 4) + (i << 4);
      int kk = tid & 15;
      As[kk][rr] = (k0 + kk < K) ? X[(size_t)(bm + rr) * K + (k0 + kk)] : 0.f;
    }
#pragma unroll
    for (int i = 0; i < 4; ++i) {
      int kk = (tid >> 6) + (i << 2);
      int c  = tid & 63;
      Bs[kk][c] = (k0 + kk < K) ? W[(size_t)(k0 + kk) * N + (bn + c)] : 0.f;
    }
    __syncthreads();
#pragma unroll
    for (int kk = 0; kk < 16; ++kk) {
      float4 av = *(const float4*)&As[kk][tr << 2];
      float4 bv = *(const float4*)&Bs[kk][tc << 2];
      float a_[4] = {av.x, av.y, av.z, av.w};
      float b_[4] = {bv.x, bv.y, bv.z, bv.w};
#pragma unroll
      for (int i = 0; i < 4; ++i)
#pragma unroll
        for (int j = 0; j < 4; ++j)
          acc[i][j] += a_[i] * b_[j];
    }
    __syncthreads();
  }
  float4 bsv = *(const float4*)&bias[bn + (tc << 2)];
  float bb[4] = {bsv.x, bsv.y, bsv.z, bsv.w};
#pragma unroll
  for (int i = 0; i < 4; ++i) {
    float v0 = acc[i][0] + bb[0], v1 = acc[i][1] + bb[1];
    float v2 = acc[i][2] + bb[2], v3 = acc[i][3] + bb[3];
    size_t ofs = (size_t)(bm + (tr << 2) + i) * N + bn + (tc << 2);
    if constexpr (OUTBF16) {
      ushort4 s4;
      s4.x = f2bf(v0); s4.y = f2bf(v1); s4.z = f2bf(v2); s4.w = f2bf(v3);
      *(ushort4*)((ushort_t*)out + ofs) = s4;
    } else {
      *(float4*)((float*)out + ofs) = make_float4(v0, v1, v2, v3);
    }
  }
}

// ---------------------------------------------------------------- Attention
// 4 targets per wave, one (target,neighbor) per lane; k/v bf16 always.
// OUTSPLIT: epilogue writes bf16 hi/lo pair (feeds next layer's MFMA GEMMs);
// else fp32 (in-place over xin).
template <int DOUT, bool OUTSPLIT>
__global__ __launch_bounds__(256) void attn_kernel(const float* __restrict__ qp,
                                                   const ushort_t* __restrict__ kp,
                                                   const ushort_t* __restrict__ vp,
                                                   const int* __restrict__ idx,
                                                   const float* xin,
                                                   void* outa,
                                                   ushort_t* outl) {
  constexpr int F   = DOUT / 4;    // float4 per row
  constexpr int CPL = DOUT / 16;   // channels per lane in PV
  __shared__ float4 qs[4][4][F + 1];
  __shared__ int    ss[4][64];
  int lane = threadIdx.x & 63, wv = threadIdx.x >> 6;
  int t0 = blockIdx.x * 16 + wv * 4;
  int bofs = (t0 >> 12) << 12;
  int tt = lane >> 4, jj = lane & 15;
  int src = bofs + idx[(t0 + tt) * 16 + jj];
  ss[wv][lane] = src;
  const float4* qp4 = (const float4*)qp;
#pragma unroll
  for (int i = 0; i < F / 16; ++i) {
    int g = lane + 64 * i;
    qs[wv][g / F][g % F] = qp4[(size_t)t0 * F + g];
  }
  __syncthreads();

  // ---- logits: full-row q.k dot per lane
  const uint4* krow = (const uint4*)(kp + (size_t)src * DOUT);
  float acc = 0.f;
#pragma unroll
  for (int cch = 0; cch < DOUT / 8; ++cch) {
    uint4 kk = krow[cch];
    float4 q0 = qs[wv][tt][2 * cch], q1 = qs[wv][tt][2 * cch + 1];
    float2 k0 = bf2(kk.x), k1 = bf2(kk.y), k2 = bf2(kk.z), k3 = bf2(kk.w);
    acc += q0.x * k0.x + q0.y * k0.y + q0.z * k1.x + q0.w * k1.y
         + q1.x * k2.x + q1.y * k2.y + q1.z * k3.x + q1.w * k3.y;
  }
  const float scale = (DOUT == 64) ? 0.125f
                    : (DOUT == 128) ? 0.08838834764831843f : 0.0625f;
  float logit = acc * scale;
  float mx = logit;
#pragma unroll
  for (int d = 1; d <= 8; d <<= 1) mx = fmaxf(mx, __shfl_xor(mx, d));
  float e = expf(logit - mx);
  float sm = e;
#pragma unroll
  for (int d = 1; d <= 8; d <<= 1) sm += __shfl_xor(sm, d);
  float a = e / sm;

  // ---- PV: lane covers channels [CPL*jj, CPL*jj+CPL)
  float4 o[CPL / 4];
#pragma unroll
  for (int c = 0; c < CPL / 4; ++c) o[c] = make_float4(0.f, 0.f, 0.f, 0.f);
  int gbase = lane & 48;
#pragma unroll
  for (int j = 0; j < 16; ++j) {
    float aj = __shfl(a, gbase | j);
    const ushort_t* vr = vp + (size_t)ss[wv][gbase | j] * DOUT + CPL * jj;
    if constexpr (CPL == 4) {
      uint2 vv = *(const uint2*)vr;
      float2 a0 = bf2(vv.x), a1 = bf2(vv.y);
      o[0].x += aj * a0.x; o[0].y += aj * a0.y;
      o[0].z += aj * a1.x; o[0].w += aj * a1.y;
    } else {
#pragma unroll
      for (int c = 0; c < CPL / 8; ++c) {
        uint4 vv = ((const uint4*)vr)[c];
        float2 a0 = bf2(vv.x), a1 = bf2(vv.y), a2 = bf2(vv.z), a3 = bf2(vv.w);
        o[2 * c].x += aj * a0.x;     o[2 * c].y += aj * a0.y;
        o[2 * c].z += aj * a1.x;     o[2 * c].w += aj * a1.y;
        o[2 * c + 1].x += aj * a2.x; o[2 * c + 1].y += aj * a2.y;
        o[2 * c + 1].z += aj * a3.x; o[2 * c + 1].w += aj * a3.y;
      }
    }
  }

  // ---- epilogue: skip add + relu, write split-bf16 or fp32
  size_t chbase = (size_t)(t0 + tt) * DOUT + CPL * jj;
  const float4* xi4 = (const float4*)(xin + chbase);
#pragma unroll
  for (int c = 0; c < CPL / 4; ++c) {
    float4 x4 = xi4[c];
    float4 r;
    r.x = fmaxf(x4.x + o[c].x, 0.f);
    r.y = fmaxf(x4.y + o[c].y, 0.f);
    r.z = fmaxf(x4.z + o[c].z, 0.f);
    r.w = fmaxf(x4.w + o[c].w, 0.f);
    if constexpr (OUTSPLIT) {
      ushort4 h, l;
      h.x = f2bf(r.x); l.x = f2bf(r.x - bff(h.x));
      h.y = f2bf(r.y); l.y = f2bf(r.y - bff(h.y));
      h.z = f2bf(r.z); l.z = f2bf(r.z - bff(h.z));
      h.w = f2bf(r.w); l.w = f2bf(r.w - bff(h.w));
      *(ushort4*)((ushort_t*)outa + chbase + 4 * c) = h;
      *(ushort4*)(outl + chbase + 4 * c) = l;
    } else {
      ((float4*)outa)[chbase / 4 + c] = r;
    }
  }
}

// ---------------------------------------------------------------- Pool + head
__global__ void zero_kernel(float* g) { g[blockIdx.x * 256 + threadIdx.x] = 0.f; }

__global__ __launch_bounds__(256) void pool_kernel(const float* __restrict__ x3,
                                                   float* __restrict__ g) {
  int b = blockIdx.y, c = threadIdx.x;
  int p0 = blockIdx.x * 256;
  float m = 0.f;
  for (int p = p0; p < p0 + 256; ++p)
    m = fmaxf(m, x3[((size_t)b * NPTS + p) * 256 + c]);
  atomicMax((int*)&g[b * 256 + c], __float_as_int(m));
}

__global__ __launch_bounds__(256) void head_kernel(const float* __restrict__ g,
    const float* __restrict__ w1, const float* __restrict__ b1,
    const float* __restrict__ w2, const float* __restrict__ b2,
    const float* __restrict__ w3, const float* __restrict__ b3,
    float* __restrict__ out) {
  __shared__ float gb[256], h1[512], h2[256], lg[10];
  int b = blockIdx.x, t = threadIdx.x;
  gb[t] = g[b * 256 + t];
  __syncthreads();
#pragma unroll
  for (int half = 0; half < 2; ++half) {
    int c = t + half * 256;
    float a = b1[c];
    for (int kk = 0; kk < 256; ++kk) a += gb[kk] * w1[kk * 512 + c];
    h1[c] = fmaxf(a, 0.f);
  }
  __syncthreads();
  {
    float a = b2[t];
    for (int kk = 0; kk < 512; ++kk) a += h1[kk] * w2[kk * 256 + t];
    h2[t] = fmaxf(a, 0.f);
  }
  __syncthreads();
  if (t < 10) {
    float a = b3[t];
    for (int kk = 0; kk < 256; ++kk) a += h2[kk] * w3[kk * 10 + t];
    lg[t] = a;
  }
  __syncthreads();
  if (t < 10) {
    float mx = lg[0];
#pragma unroll
    for (int i = 1; i < 10; ++i) mx = fmaxf(mx, lg[i]);
    float s = 0.f;
#pragma unroll
    for (int i = 0; i < 10; ++i) s += expf(lg[i] - mx);
    out[b * 10 + t] = lg[t] - mx - logf(s);
  }
}

// ---------------------------------------------------------------- launch
extern "C" void kernel_launch(void* const* d_in, const int* in_sizes, int n_in,
                              void* d_out, int out_size, void* d_ws, size_t ws_size,
                              hipStream_t stream) {
  const float* pos = (const float*)d_in[0];
  const float* W[3][4]; const float* Bb[3][4];
  for (int l = 0; l < 3; ++l)
    for (int nm = 0; nm < 4; ++nm) {           // order q,k,v,s
      W[l][nm]  = (const float*)d_in[1 + l * 8 + nm * 2];
      Bb[l][nm] = (const float*)d_in[1 + l * 8 + nm * 2 + 1];
    }
  const float* fc1w = (const float*)d_in[25]; const float* fc1b = (const float*)d_in[26];
  const float* fc2w = (const float*)d_in[27]; const float* fc2b = (const float*)d_in[28];
  const float* fc3w = (const float*)d_in[29]; const float* fc3b = (const float*)d_in[30];

  int*   idxb  = (int*)d_ws;
  float* fbase = (float*)((char*)d_ws + (size_t)MTOT * NBR * 4);
  float* qb = fbase;
  float* kb = qb + (size_t)MTOT * 256;
  float* vb = kb + (size_t)MTOT * 256;
  float* x1 = vb + (size_t)MTOT * 256;
  float* x2 = x1 + (size_t)MTOT * 64;
  float* x3 = x2 + (size_t)MTOT * 128;
  float* g  = x3 + (size_t)MTOT * 256;
  float4* pos4 = (float4*)(g + BATCH * 256);
  ushort_t* xsh = (ushort_t*)(pos4 + MTOT);
  ushort_t* xsl = xsh + (size_t)MTOT * 128;
  ushort_t* wsp = xsl + (size_t)MTOT * 128;   // 8 buffers of 32768 ushorts
  ushort_t* kh = (ushort_t*)kb;
  ushort_t* vh = (ushort_t*)vb;

  prep_pos4<<<MTOT / 256, 256, 0, stream>>>(pos, pos4);
  knn_kernel<<<MTOT, 256, 0, stream>>>(pos4, idxb);

  // layer 1: din=3, dout=64 (vector GEMM; k/v bf16 out, q/s fp32)
  gemm_bias<false><<<dim3(512, 1), 256, 0, stream>>>(pos, W[0][0], Bb[0][0], qb, 3, 64);
  gemm_bias<true ><<<dim3(512, 1), 256, 0, stream>>>(pos, W[0][1], Bb[0][1], kh, 3, 64);
  gemm_bias<true ><<<dim3(512, 1), 256, 0, stream>>>(pos, W[0][2], Bb[0][2], vh, 3, 64);
  gemm_bias<false><<<dim3(512, 1), 256, 0, stream>>>(pos, W[0][3], Bb[0][3], x1, 3, 64);
  attn_kernel<64, true><<<MTOT / 16, 256, 0, stream>>>(qb, kh, vh, idxb, x1, xsh, xsl);

  // layer 2: din=64, dout=128 — split-bf16 MFMA GEMMs (x already split by attn)
  {
    void* outs[4] = {qb, kh, vh, x2};
    for (int nm = 0; nm < 4; ++nm) {
      ushort_t* th = wsp + nm * 2 * 32768;
      ushort_t* tl = th + 32768;
      split_wt<<<(64 * 128 + 255) / 256, 256, 0, stream>>>(W[1][nm], th, tl, 64, 128);
      if (nm == 1 || nm == 2)
        gemm_mfma<true ><<<dim3(512, 2), 256, 0, stream>>>(xsh, xsl, th, tl, Bb[1][nm], outs[nm], 64, 128);
      else
        gemm_mfma<false><<<dim3(512, 2), 256, 0, stream>>>(xsh, xsl, th, tl, Bb[1][nm], outs[nm], 64, 128);
    }
  }
  attn_kernel<128, true><<<MTOT / 16, 256, 0, stream>>>(qb, kh, vh, idxb, x2, xsh, xsl);

  // layer 3: din=128, dout=256
  {
    void* outs[4] = {qb, kh, vh, x3};
    for (int nm = 0; nm < 4; ++nm) {
      ushort_t* th = wsp + nm * 2 * 32768;
      ushort_t* tl = th + 32768;
      split_wt<<<(128 * 256 + 255) / 256, 256, 0, stream>>>(W[2][nm], th, tl, 128, 256);
      if (nm == 1 || nm == 2)
        gemm_mfma<true ><<<dim3(512, 4), 256, 0, stream>>>(xsh, xsl, th, tl, Bb[2][nm], outs[nm], 128, 256);
      else
        gemm_mfma<false><<<dim3(512, 4), 256, 0, stream>>>(xsh, xsl, th, tl, Bb[2][nm], outs[nm], 128, 256);
    }
  }
  attn_kernel<256, false><<<MTOT / 16, 256, 0, stream>>>(qb, kh, vh, idxb, x3, x3, nullptr);

  // global max pool + MLP head
  zero_kernel<<<8, 256, 0, stream>>>(g);
  pool_kernel<<<dim3(16, 8), 256, 0, stream>>>(x3, g);
  head_kernel<<<8, 256, 0, stream>>>(g, fc1w, fc1b, fc2w, fc2b, fc3w, fc3b,
                                     (float*)d_out);
}

// Round 7
// 528.182 us; speedup vs baseline: 3.6270x; 1.0520x over previous
//
#include <hip/hip_runtime.h>
#include <math.h>

#define BATCH 8
#define NPTS  4096
#define NBR   16
#define MTOT  (BATCH * NPTS)   // 32768

#define KNN_BINS  2048                        // top-11 bits of fp32 d2 (diff form, >=0)
#define KNN_SHIFT 21
#define KNN_PAD   (KNN_BINS + KNN_BINS / 32)  // pad word every 32 bins -> 2112
#define HADDR(b)  ((b) + ((b) >> 5))
#define KNN_CAP   384

typedef unsigned short ushort_t;
typedef __attribute__((ext_vector_type(8))) short bf16x8;
typedef __attribute__((ext_vector_type(4))) float f32x4;

__device__ inline unsigned short f2bf(float f) {   // RNE bf16 bits
  unsigned u = __float_as_uint(f);
  return (unsigned short)((u + 0x7FFFu + ((u >> 16) & 1u)) >> 16);
}
__device__ inline float bff(unsigned short h) {
  return __uint_as_float(((unsigned)h) << 16);
}
__device__ inline float2 bf2(unsigned u) {         // two packed bf16 -> floats
  return make_float2(__uint_as_float(u << 16), __uint_as_float(u & 0xFFFF0000u));
}

// ---------------------------------------------------------------- prep
__global__ __launch_bounds__(256) void prep_pos4(const float* __restrict__ pos,
                                                 float4* __restrict__ pos4) {
  int i = blockIdx.x * 256 + threadIdx.x;
  float x = pos[i * 3 + 0], y = pos[i * 3 + 1], z = pos[i * 3 + 2];
  pos4[i] = make_float4(x, y, z, x * x + y * y + z * z);
}

// ---------------------------------------------------------------- KNN v5
// One block = one target. Select via THREAD-MINIMA histogram:
//  A) thread computes 16 diff-form fp32 d2 keys, tracks its min.
//  B) histogram the 256 minima (256 atomics/block, not 4096); bin B where
//     cum>=16 gives threshold tau = upper edge of B. Proof: >=16 distinct
//     threads have an element <= tau; and if the true 16th were above B,
//     fewer than 16 elements (hence minima) would lie <= B. So top-16 all
//     have key>>21 <= B.
//  C) survivors (~30-60) get exact REFERENCE-formula keys (|p|^2+|q|^2-2pq,
//     flip-mapped, index-embedded u64); rank-by-counting emits op[rank]=idx.
//     Tie-break = smaller index, matching lax.top_k.
__global__ __launch_bounds__(256) void knn_kernel(const float4* __restrict__ pos4,
                                                  int* __restrict__ idxout) {
  __shared__ unsigned hist[KNN_PAD];
  __shared__ unsigned wsum[4];
  __shared__ unsigned long long cand[KNN_CAP];
  __shared__ unsigned nC, s_bmin;

  int t = blockIdx.x;
  int b = t >> 12;
  int p = t & (NPTS - 1);
  const float4* base = pos4 + ((size_t)b << 12);
  float4 me = base[p];

  int tid = threadIdx.x;
  int lane = tid & 63, wv = tid >> 6;
#pragma unroll
  for (int i = 0; i < 9; ++i) {
    int w = tid + i * 256;
    if (w < KNN_PAD) hist[w] = 0;
  }
  if (tid == 0) nC = 0;
  __syncthreads();

  // ---- phase A: 16 diff-form keys + running min
  unsigned key[16];
  unsigned mn = 0xFFFFFFFFu;
#pragma unroll
  for (int j = 0; j < 16; ++j) {
    int q = tid + j * 256;
    float4 o = base[q];
    float dx = me.x - o.x, dy = me.y - o.y, dz = me.z - o.z;
    float d2 = dx * dx + dy * dy + dz * dz;          // >= 0: bits are monotone
    unsigned k = __float_as_uint(d2);
    key[j] = (q == p) ? 0xFFFFFFFFu : k;             // exclude self
    mn = (key[j] < mn) ? key[j] : mn;
  }
  atomicAdd(&hist[HADDR(mn >> KNN_SHIFT)], 1u);
  __syncthreads();

  // ---- find bin B where cum(minima) >= 16 (8 bins per thread + wave scan)
  unsigned s = 0;
#pragma unroll
  for (int i = 0; i < 8; ++i) s += hist[HADDR(tid * 8 + i)];
  unsigned c = s;
#pragma unroll
  for (int d = 1; d < 64; d <<= 1) {
    unsigned x = __shfl_up(c, d);
    if (lane >= d) c += x;
  }
  if (lane == 63) wsum[wv] = c;
  __syncthreads();
  unsigned off = 0;
#pragma unroll
  for (int w = 0; w < 4; ++w) off += (w < wv) ? wsum[w] : 0u;
  unsigned cum_incl = c + off;
  unsigned cum_excl = cum_incl - s;

  if (cum_excl < NBR && cum_incl >= NBR) {   // unique owner thread
    unsigned h[8];
#pragma unroll
    for (int i = 0; i < 8; ++i) h[i] = hist[HADDR(tid * 8 + i)];
    unsigned c0 = cum_excl; int bin = tid * 8; bool done = false;
#pragma unroll
    for (int i = 0; i < 8; ++i) {
      if (!done) {
        if (c0 + h[i] >= NBR) done = true;
        else { c0 += h[i]; ++bin; }
      }
    }
    s_bmin = (unsigned)bin;
  }
  __syncthreads();
  unsigned bmin = s_bmin;

  // ---- phase B: collect survivors with EXACT reference-formula keys
#pragma unroll
  for (int j = 0; j < 16; ++j) {
    if ((key[j] >> KNN_SHIFT) <= bmin) {
      int q = tid + j * 256;
      float4 o = base[q];
      float d2r = me.w + o.w - 2.f * (me.x * o.x + me.y * o.y + me.z * o.z);
      unsigned u = __float_as_uint(d2r);
      unsigned fk = u ^ (unsigned)(((int)u >> 31) | 0x80000000);  // order flip
      unsigned slot = atomicAdd(&nC, 1u);
      if (slot < KNN_CAP)
        cand[slot] = ((unsigned long long)fk << 32) | (unsigned)q;
    }
  }
  __syncthreads();

  // ---- phase C: rank-by-counting, emit op[rank] = idx for rank < 16
  int n = (int)(nC < KNN_CAP ? nC : KNN_CAP);
  int* op = idxout + (size_t)t * NBR;
  for (int sidx = tid; sidx < n; sidx += 256) {
    unsigned long long my = cand[sidx];
    int cnt = 0;
    for (int r = 0; r < n; ++r) cnt += (cand[r] < my) ? 1 : 0;
    if (cnt < NBR) op[cnt] = (int)(my & 0xFFFFFFFFu);
  }
}

// ---------------------------------------------------------------- weight split
// W[K][N] fp32 -> transposed Wt[N][K] bf16 hi/lo
__global__ __launch_bounds__(256) void split_wt(const float* __restrict__ w,
                                                ushort_t* __restrict__ th,
                                                ushort_t* __restrict__ tl,
                                                int K, int N) {
  int i = blockIdx.x * 256 + threadIdx.x;
  if (i >= K * N) return;
  int k = i / N, n = i - k * N;
  float v = w[i];
  unsigned short h = f2bf(v);
  th[(size_t)n * K + k] = h;
  tl[(size_t)n * K + k] = f2bf(v - bff(h));
}

// ---------------------------------------------------------------- MFMA GEMM (split bf16)
template <bool OUTBF16>
__global__ __launch_bounds__(256) void gemm_mfma(const ushort_t* __restrict__ Xh,
                                                 const ushort_t* __restrict__ Xl,
                                                 const ushort_t* __restrict__ Wh,
                                                 const ushort_t* __restrict__ Wl,
                                                 const float* __restrict__ bias,
                                                 void* __restrict__ out,
                                                 int K, int N) {
  int lane = threadIdx.x & 63, wv = threadIdx.x >> 6;
  int bm = blockIdx.x * 64 + (wv >> 1) * 32;
  int bn = blockIdx.y * 64 + (wv & 1) * 32;
  int r = lane & 15, g4 = lane >> 4;
  f32x4 acc[2][2];
#pragma unroll
  for (int i = 0; i < 2; ++i)
#pragma unroll
    for (int j = 0; j < 2; ++j) acc[i][j] = (f32x4){0.f, 0.f, 0.f, 0.f};

  for (int k0 = 0; k0 < K; k0 += 32) {
    int kb = k0 + g4 * 8;
    bf16x8 ah[2], al[2], bh[2], bl[2];
#pragma unroll
    for (int i = 0; i < 2; ++i) {
      size_t xo = (size_t)(bm + i * 16 + r) * K + kb;
      ah[i] = *(const bf16x8*)(Xh + xo);
      al[i] = *(const bf16x8*)(Xl + xo);
      size_t wo = (size_t)(bn + i * 16 + r) * K + kb;
      bh[i] = *(const bf16x8*)(Wh + wo);
      bl[i] = *(const bf16x8*)(Wl + wo);
    }
#pragma unroll
    for (int i = 0; i < 2; ++i)
#pragma unroll
      for (int j = 0; j < 2; ++j) {
        acc[i][j] = __builtin_amdgcn_mfma_f32_16x16x32_bf16(ah[i], bh[j], acc[i][j], 0, 0, 0);
        acc[i][j] = __builtin_amdgcn_mfma_f32_16x16x32_bf16(ah[i], bl[j], acc[i][j], 0, 0, 0);
        acc[i][j] = __builtin_amdgcn_mfma_f32_16x16x32_bf16(al[i], bh[j], acc[i][j], 0, 0, 0);
      }
  }
#pragma unroll
  for (int i = 0; i < 2; ++i)
#pragma unroll
    for (int j = 0; j < 2; ++j) {
      int col = bn + j * 16 + r;
      float bv = bias[col];
#pragma unroll
      for (int tr = 0; tr < 4; ++tr) {
        int row = bm + i * 16 + g4 * 4 + tr;
        float val = acc[i][j][tr] + bv;
        if constexpr (OUTBF16)
          ((ushort_t*)out)[(size_t)row * N + col] = f2bf(val);
        else
          ((float*)out)[(size_t)row * N + col] = val;
      }
    }
}

// ---------------------------------------------------------------- GEMM (vector, layer-1 K=3)
template <bool OUTBF16>
__global__ __launch_bounds__(256) void gemm_bias(const float* __restrict__ X,
                                                 const float* __restrict__ W,
                                                 const float* __restrict__ bias,
                                                 void* __restrict__ out,
                                                 int K, int N) {
  __shared__ float As[16][68];
  __shared__ float Bs[16][64];
  int tid = threadIdx.x;
  int bm = blockIdx.x * 64;
  int bn = blockIdx.y * 64;
  int tr = tid >> 4, tc = tid & 15;
  float acc[4][4] = {{0.f}};
  for (int k0 = 0; k0 < K; k0 += 16) {
#pragma unroll
    for (int i = 0; i < 4; ++i) {
      int rr = (tid >> 4) + (i << 4);
      int kk = tid & 15;
      As[kk][rr] = (k0 + kk < K) ? X[(size_t)(bm + rr) * K + (k0 + kk)] : 0.f;
    }
#pragma unroll
    for (int i = 0; i < 4; ++i) {
      int kk = (tid >> 6) + (i << 2);
      int c  = tid & 63;
      Bs[kk][c] = (k0 + kk < K) ? W[(size_t)(k0 + kk) * N + (bn + c)] : 0.f;
    }
    __syncthreads();
#pragma unroll
    for (int kk = 0; kk < 16; ++kk) {
      float4 av = *(const float4*)&As[kk][tr << 2];
      float4 bv = *(const float4*)&Bs[kk][tc << 2];
      float a_[4] = {av.x, av.y, av.z, av.w};
      float b_[4] = {bv.x, bv.y, bv.z, bv.w};
#pragma unroll
      for (int i = 0; i < 4; ++i)
#pragma unroll
        for (int j = 0; j < 4; ++j)
          acc[i][j] += a_[i] * b_[j];
    }
    __syncthreads();
  }
  float4 bsv = *(const float4*)&bias[bn + (tc << 2)];
  float bb[4] = {bsv.x, bsv.y, bsv.z, bsv.w};
#pragma unroll
  for (int i = 0; i < 4; ++i) {
    float v0 = acc[i][0] + bb[0], v1 = acc[i][1] + bb[1];
    float v2 = acc[i][2] + bb[2], v3 = acc[i][3] + bb[3];
    size_t ofs = (size_t)(bm + (tr << 2) + i) * N + bn + (tc << 2);
    if constexpr (OUTBF16) {
      ushort4 s4;
      s4.x = f2bf(v0); s4.y = f2bf(v1); s4.z = f2bf(v2); s4.w = f2bf(v3);
      *(ushort4*)((ushort_t*)out + ofs) = s4;
    } else {
      *(float4*)((float*)out + ofs) = make_float4(v0, v1, v2, v3);
    }
  }
}

// ---------------------------------------------------------------- Attention
template <int DOUT, bool OUTSPLIT>
__global__ __launch_bounds__(256) void attn_kernel(const float* __restrict__ qp,
                                                   const ushort_t* __restrict__ kp,
                                                   const ushort_t* __restrict__ vp,
                                                   const int* __restrict__ idx,
                                                   const float* xin,
                                                   void* outa,
                                                   ushort_t* outl) {
  constexpr int F   = DOUT / 4;    // float4 per row
  constexpr int CPL = DOUT / 16;   // channels per lane in PV
  __shared__ float4 qs[4][4][F + 1];
  __shared__ int    ss[4][64];
  int lane = threadIdx.x & 63, wv = threadIdx.x >> 6;
  int t0 = blockIdx.x * 16 + wv * 4;
  int bofs = (t0 >> 12) << 12;
  int tt = lane >> 4, jj = lane & 15;
  int src = bofs + idx[(t0 + tt) * 16 + jj];
  ss[wv][lane] = src;
  const float4* qp4 = (const float4*)qp;
#pragma unroll
  for (int i = 0; i < F / 16; ++i) {
    int g = lane + 64 * i;
    qs[wv][g / F][g % F] = qp4[(size_t)t0 * F + g];
  }
  __syncthreads();

  const uint4* krow = (const uint4*)(kp + (size_t)src * DOUT);
  float acc = 0.f;
#pragma unroll
  for (int cch = 0; cch < DOUT / 8; ++cch) {
    uint4 kk = krow[cch];
    float4 q0 = qs[wv][tt][2 * cch], q1 = qs[wv][tt][2 * cch + 1];
    float2 k0 = bf2(kk.x), k1 = bf2(kk.y), k2 = bf2(kk.z), k3 = bf2(kk.w);
    acc += q0.x * k0.x + q0.y * k0.y + q0.z * k1.x + q0.w * k1.y
         + q1.x * k2.x + q1.y * k2.y + q1.z * k3.x + q1.w * k3.y;
  }
  const float scale = (DOUT == 64) ? 0.125f
                    : (DOUT == 128) ? 0.08838834764831843f : 0.0625f;
  float logit = acc * scale;
  float mx = logit;
#pragma unroll
  for (int d = 1; d <= 8; d <<= 1) mx = fmaxf(mx, __shfl_xor(mx, d));
  float e = expf(logit - mx);
  float sm = e;
#pragma unroll
  for (int d = 1; d <= 8; d <<= 1) sm += __shfl_xor(sm, d);
  float a = e / sm;

  float4 o[CPL / 4];
#pragma unroll
  for (int c = 0; c < CPL / 4; ++c) o[c] = make_float4(0.f, 0.f, 0.f, 0.f);
  int gbase = lane & 48;
#pragma unroll
  for (int j = 0; j < 16; ++j) {
    float aj = __shfl(a, gbase | j);
    const ushort_t* vr = vp + (size_t)ss[wv][gbase | j] * DOUT + CPL * jj;
    if constexpr (CPL == 4) {
      uint2 vv = *(const uint2*)vr;
      float2 a0 = bf2(vv.x), a1 = bf2(vv.y);
      o[0].x += aj * a0.x; o[0].y += aj * a0.y;
      o[0].z += aj * a1.x; o[0].w += aj * a1.y;
    } else {
#pragma unroll
      for (int c = 0; c < CPL / 8; ++c) {
        uint4 vv = ((const uint4*)vr)[c];
        float2 a0 = bf2(vv.x), a1 = bf2(vv.y), a2 = bf2(vv.z), a3 = bf2(vv.w);
        o[2 * c].x += aj * a0.x;     o[2 * c].y += aj * a0.y;
        o[2 * c].z += aj * a1.x;     o[2 * c].w += aj * a1.y;
        o[2 * c + 1].x += aj * a2.x; o[2 * c + 1].y += aj * a2.y;
        o[2 * c + 1].z += aj * a3.x; o[2 * c + 1].w += aj * a3.y;
      }
    }
  }

  size_t chbase = (size_t)(t0 + tt) * DOUT + CPL * jj;
  const float4* xi4 = (const float4*)(xin + chbase);
#pragma unroll
  for (int c = 0; c < CPL / 4; ++c) {
    float4 x4 = xi4[c];
    float4 r;
    r.x = fmaxf(x4.x + o[c].x, 0.f);
    r.y = fmaxf(x4.y + o[c].y, 0.f);
    r.z = fmaxf(x4.z + o[c].z, 0.f);
    r.w = fmaxf(x4.w + o[c].w, 0.f);
    if constexpr (OUTSPLIT) {
      ushort4 h, l;
      h.x = f2bf(r.x); l.x = f2bf(r.x - bff(h.x));
      h.y = f2bf(r.y); l.y = f2bf(r.y - bff(h.y));
      h.z = f2bf(r.z); l.z = f2bf(r.z - bff(h.z));
      h.w = f2bf(r.w); l.w = f2bf(r.w - bff(h.w));
      *(ushort4*)((ushort_t*)outa + chbase + 4 * c) = h;
      *(ushort4*)(outl + chbase + 4 * c) = l;
    } else {
      ((float4*)outa)[chbase / 4 + c] = r;
    }
  }
}

// ---------------------------------------------------------------- Pool + head
__global__ void zero_kernel(float* g) { g[blockIdx.x * 256 + threadIdx.x] = 0.f; }

__global__ __launch_bounds__(256) void pool_kernel(const float* __restrict__ x3,
                                                   float* __restrict__ g) {
  int b = blockIdx.y, c = threadIdx.x;
  int p0 = blockIdx.x * 256;
  float m = 0.f;
  for (int p = p0; p < p0 + 256; ++p)
    m = fmaxf(m, x3[((size_t)b * NPTS + p) * 256 + c]);
  atomicMax((int*)&g[b * 256 + c], __float_as_int(m));
}

__global__ __launch_bounds__(256) void head_kernel(const float* __restrict__ g,
    const float* __restrict__ w1, const float* __restrict__ b1,
    const float* __restrict__ w2, const float* __restrict__ b2,
    const float* __restrict__ w3, const float* __restrict__ b3,
    float* __restrict__ out) {
  __shared__ float gb[256], h1[512], h2[256], lg[10];
  int b = blockIdx.x, t = threadIdx.x;
  gb[t] = g[b * 256 + t];
  __syncthreads();
#pragma unroll
  for (int half = 0; half < 2; ++half) {
    int c = t + half * 256;
    float a = b1[c];
    for (int kk = 0; kk < 256; ++kk) a += gb[kk] * w1[kk * 512 + c];
    h1[c] = fmaxf(a, 0.f);
  }
  __syncthreads();
  {
    float a = b2[t];
    for (int kk = 0; kk < 512; ++kk) a += h1[kk] * w2[kk * 256 + t];
    h2[t] = fmaxf(a, 0.f);
  }
  __syncthreads();
  if (t < 10) {
    float a = b3[t];
    for (int kk = 0; kk < 256; ++kk) a += h2[kk] * w3[kk * 10 + t];
    lg[t] = a;
  }
  __syncthreads();
  if (t < 10) {
    float mx = lg[0];
#pragma unroll
    for (int i = 1; i < 10; ++i) mx = fmaxf(mx, lg[i]);
    float s = 0.f;
#pragma unroll
    for (int i = 0; i < 10; ++i) s += expf(lg[i] - mx);
    out[b * 10 + t] = lg[t] - mx - logf(s);
  }
}

// ---------------------------------------------------------------- launch
extern "C" void kernel_launch(void* const* d_in, const int* in_sizes, int n_in,
                              void* d_out, int out_size, void* d_ws, size_t ws_size,
                              hipStream_t stream) {
  const float* pos = (const float*)d_in[0];
  const float* W[3][4]; const float* Bb[3][4];
  for (int l = 0; l < 3; ++l)
    for (int nm = 0; nm < 4; ++nm) {           // order q,k,v,s
      W[l][nm]  = (const float*)d_in[1 + l * 8 + nm * 2];
      Bb[l][nm] = (const float*)d_in[1 + l * 8 + nm * 2 + 1];
    }
  const float* fc1w = (const float*)d_in[25]; const float* fc1b = (const float*)d_in[26];
  const float* fc2w = (const float*)d_in[27]; const float* fc2b = (const float*)d_in[28];
  const float* fc3w = (const float*)d_in[29]; const float* fc3b = (const float*)d_in[30];

  int*   idxb  = (int*)d_ws;
  float* fbase = (float*)((char*)d_ws + (size_t)MTOT * NBR * 4);
  float* qb = fbase;
  float* kb = qb + (size_t)MTOT * 256;
  float* vb = kb + (size_t)MTOT * 256;
  float* x1 = vb + (size_t)MTOT * 256;
  float* x2 = x1 + (size_t)MTOT * 64;
  float* x3 = x2 + (size_t)MTOT * 128;
  float* g  = x3 + (size_t)MTOT * 256;
  float4* pos4 = (float4*)(g + BATCH * 256);
  ushort_t* xsh = (ushort_t*)(pos4 + MTOT);
  ushort_t* xsl = xsh + (size_t)MTOT * 128;
  ushort_t* wsp = xsl + (size_t)MTOT * 128;   // 8 buffers of 32768 ushorts
  ushort_t* kh = (ushort_t*)kb;
  ushort_t* vh = (ushort_t*)vb;

  prep_pos4<<<MTOT / 256, 256, 0, stream>>>(pos, pos4);
  knn_kernel<<<MTOT, 256, 0, stream>>>(pos4, idxb);

  // layer 1: din=3, dout=64 (vector GEMM; k/v bf16 out, q/s fp32)
  gemm_bias<false><<<dim3(512, 1), 256, 0, stream>>>(pos, W[0][0], Bb[0][0], qb, 3, 64);
  gemm_bias<true ><<<dim3(512, 1), 256, 0, stream>>>(pos, W[0][1], Bb[0][1], kh, 3, 64);
  gemm_bias<true ><<<dim3(512, 1), 256, 0, stream>>>(pos, W[0][2], Bb[0][2], vh, 3, 64);
  gemm_bias<false><<<dim3(512, 1), 256, 0, stream>>>(pos, W[0][3], Bb[0][3], x1, 3, 64);
  attn_kernel<64, true><<<MTOT / 16, 256, 0, stream>>>(qb, kh, vh, idxb, x1, xsh, xsl);

  // layer 2: din=64, dout=128 — split-bf16 MFMA GEMMs (x already split by attn)
  {
    void* outs[4] = {qb, kh, vh, x2};
    for (int nm = 0; nm < 4; ++nm) {
      ushort_t* th = wsp + nm * 2 * 32768;
      ushort_t* tl = th + 32768;
      split_wt<<<(64 * 128 + 255) / 256, 256, 0, stream>>>(W[1][nm], th, tl, 64, 128);
      if (nm == 1 || nm == 2)
        gemm_mfma<true ><<<dim3(512, 2), 256, 0, stream>>>(xsh, xsl, th, tl, Bb[1][nm], outs[nm], 64, 128);
      else
        gemm_mfma<false><<<dim3(512, 2), 256, 0, stream>>>(xsh, xsl, th, tl, Bb[1][nm], outs[nm], 64, 128);
    }
  }
  attn_kernel<128, true><<<MTOT / 16, 256, 0, stream>>>(qb, kh, vh, idxb, x2, xsh, xsl);

  // layer 3: din=128, dout=256
  {
    void* outs[4] = {qb, kh, vh, x3};
    for (int nm = 0; nm < 4; ++nm) {
      ushort_t* th = wsp + nm * 2 * 32768;
      ushort_t* tl = th + 32768;
      split_wt<<<(128 * 256 + 255) / 256, 256, 0, stream>>>(W[2][nm], th, tl, 128, 256);
      if (nm == 1 || nm == 2)
        gemm_mfma<true ><<<dim3(512, 4), 256, 0, stream>>>(xsh, xsl, th, tl, Bb[2][nm], outs[nm], 128, 256);
      else
        gemm_mfma<false><<<dim3(512, 4), 256, 0, stream>>>(xsh, xsl, th, tl, Bb[2][nm], outs[nm], 128, 256);
    }
  }
  attn_kernel<256, false><<<MTOT / 16, 256, 0, stream>>>(qb, kh, vh, idxb, x3, x3, nullptr);

  // global max pool + MLP head
  zero_kernel<<<8, 256, 0, stream>>>(g);
  pool_kernel<<<dim3(16, 8), 256, 0, stream>>>(x3, g);
  head_kernel<<<8, 256, 0, stream>>>(g, fc1w, fc1b, fc2w, fc2b, fc3w, fc3b,
                                     (float*)d_out);
}